// Round 8
// baseline (192.291 us; speedup 1.0000x reference)
//
#include <hip/hip_runtime.h>
#include <hip/hip_bf16.h>
#include <math.h>

#define B_ 4
#define T_ 2048
#define D_ 128
#define H_ 8
#define BT_ 8192
#define HD_ 1024

typedef __attribute__((ext_vector_type(8))) short bf16x8;
typedef __attribute__((ext_vector_type(4))) float f32x4;

__device__ __forceinline__ short f2bf(float f) {
  union { float f; unsigned u; } v; v.f = f;
  return (short)((v.u + 0x8000u) >> 16);
}

#if __has_builtin(__builtin_amdgcn_exp2f)
#define EXP2F(x) __builtin_amdgcn_exp2f(x)
#else
#define EXP2F(x) exp2f(x)
#endif

#define QSCALE 0.12752040242046492f   // k^-0.5 * log2(e), folded into Q
#define VSCALE 0.29730177875068026f   // k^-0.25, folded into V

// async global->LDS DMA, 16B/lane; LDS dest = wave-uniform base + lane*16
__device__ __forceinline__ void gld16(const short* g, short* l) {
  __builtin_amdgcn_global_load_lds(
      (const __attribute__((address_space(1))) void*)g,
      (__attribute__((address_space(3))) void*)l, 16, 0, 0);
}

// ---------------------------------------------------------------------------
// Kernel 0: prep. blocks 0..23: Wq/Wk/Wv -> WT swizzled tile images.
// blocks 24..87: x -> xbf swizzled tile images.
// ---------------------------------------------------------------------------
__global__ __launch_bounds__(256) void prep(
    const float* __restrict__ x, const float* __restrict__ Wq,
    const float* __restrict__ Wk, const float* __restrict__ Wv,
    short* __restrict__ xbf, short* __restrict__ WT)
{
  __shared__ __align__(16) short Tt[128*128];
  const int tid = threadIdx.x;
  const int id = blockIdx.x;
  if (id < 24) {
    const int wsel = id >> 3, nt = id & 7;
    const float* W = (wsel == 0) ? Wq : (wsel == 1) ? Wk : Wv;
    #pragma unroll 4
    for (int i = tid; i < 4096; i += 256) {
      int k = i >> 5, n4 = (i & 31) << 2;
      float4 v = *(const float4*)&W[(size_t)k * HD_ + nt*128 + n4];
      float vv[4] = {v.x, v.y, v.z, v.w};
      #pragma unroll
      for (int j = 0; j < 4; j++) {
        int n = n4 + j;
        Tt[n*128 + (((k >> 3) ^ (n & 15)) << 3) + (k & 7)] = f2bf(vv[j]);
      }
    }
    __syncthreads();
    short* dst = WT + (size_t)id * 16384;
    #pragma unroll 2
    for (int i = tid; i < 2048; i += 256)
      *(bf16x8*)&dst[i*8] = *(bf16x8*)&Tt[i*8];
  } else {
    const int xb = id - 24;                       // 64 tiles
    const float* xs = x + (size_t)xb * 16384;
    short* dst = xbf + (size_t)xb * 16384;
    #pragma unroll 4
    for (int i = tid; i < 4096; i += 256) {
      float4 v = ((const float4*)xs)[i];
      int row = i >> 5, c = (i & 31) >> 1, half = i & 1;
      short4 p;
      p.x = f2bf(v.x); p.y = f2bf(v.y); p.z = f2bf(v.z); p.w = f2bf(v.w);
      *(short4*)&dst[(row*16 + (c ^ (row & 15)))*8 + half*4] = p;
    }
  }
}

// ---------------------------------------------------------------------------
// Kernel 1: QKV GEMM, fully DMA-staged. grid (64 m, 24 n=wsel*8+head).
// Q AND K stored as pre-swizzled 16KB tiles (64t x 128d); V transposed
// tiles (128d x 64t). Epilogue: LDS image + linear 32KB b128 copy-out.
// ---------------------------------------------------------------------------
__global__ __launch_bounds__(256, 2) void qkv_proj(
    const short* __restrict__ xbf, const short* __restrict__ WT,
    short* __restrict__ Qw, short* __restrict__ Kw, short* __restrict__ Vw)
{
  __shared__ __align__(16) short As[16384];
  __shared__ __align__(16) short Bs[16384];
  const int tid = threadIdx.x;
  const int w = tid >> 6, lane = tid & 63, quad = lane >> 4, l16 = lane & 15;
  const int m0 = blockIdx.x * 128;

  {
    const short* asrc = xbf + (size_t)blockIdx.x * 16384;
    const short* bsrc = WT + (size_t)blockIdx.y * 16384;
    const int so = w*4096 + lane*8;
    #pragma unroll
    for (int cc = 0; cc < 8; cc++) {
      gld16(asrc + so + cc*512, &As[w*4096 + cc*512]);
      gld16(bsrc + so + cc*512, &Bs[w*4096 + cc*512]);
    }
  }
  __syncthreads();

  const int wm = (w & 1) * 64, wn = (w >> 1) * 64;
  f32x4 acc[4][4];
  #pragma unroll
  for (int a = 0; a < 4; a++)
    #pragma unroll
    for (int b = 0; b < 4; b++) acc[a][b] = (f32x4){0.f, 0.f, 0.f, 0.f};

  #pragma unroll
  for (int kk = 0; kk < 4; kk++) {
    const int swz = ((kk*4 + quad) ^ l16) << 3;
    bf16x8 af[4], bfv[4];
    #pragma unroll
    for (int mi = 0; mi < 4; mi++) af[mi]  = *(bf16x8*)&As[(wm + mi*16 + l16)*128 + swz];
    #pragma unroll
    for (int ni = 0; ni < 4; ni++) bfv[ni] = *(bf16x8*)&Bs[(wn + ni*16 + l16)*128 + swz];
    #pragma unroll
    for (int mi = 0; mi < 4; mi++)
      #pragma unroll
      for (int ni = 0; ni < 4; ni++)
        acc[mi][ni] = __builtin_amdgcn_mfma_f32_16x16x32_bf16(af[mi], bfv[ni], acc[mi][ni], 0, 0, 0);
  }

  __syncthreads();     // all MFMA reads of As/Bs done; reuse As as image
  const int wsel = (int)blockIdx.y >> 3;
  #pragma unroll
  for (int mi = 0; mi < 4; mi++) {
    #pragma unroll
    for (int ni = 0; ni < 4; ni++) {
      const int t0l = wm + mi*16 + quad*4;        // local t rows t0l..t0l+3
      const int d   = wn + ni*16 + l16;           // local d
      if (wsel <= 1) {                            // Q and K: same tile swizzle
        const float sc = wsel ? 1.0f : QSCALE;
        const int c = d >> 3;
        #pragma unroll
        for (int r = 0; r < 4; r++) {
          const int tl = (t0l + r) & 63, tile = (t0l + r) >> 6;
          As[tile*8192 + tl*128 + ((c ^ (tl & 15)) << 3) + (d & 7)] =
              f2bf(acc[mi][ni][r] * sc);
        }
      } else {                                    // V: transposed tile
        #pragma unroll
        for (int r = 0; r < 4; r++) {
          const int tl = (t0l + r) & 63, tile = (t0l + r) >> 6;
          As[tile*8192 + d*64 + (((tl >> 3) ^ (d & 7)) << 3) + (tl & 7)] =
              f2bf(acc[mi][ni][r] * VSCALE);
        }
      }
    }
  }
  __syncthreads();

  const int h = (int)blockIdx.y & 7;
  const int b = m0 >> 11, t0 = m0 & 2047;
  short* base = ((wsel == 0) ? Qw : (wsel == 1) ? Kw : Vw)
              + (size_t)(b*H_ + h)*262144 + (size_t)t0*128;
  #pragma unroll 2
  for (int i = tid; i < 2048; i += 256)
    *(bf16x8*)&base[i*8] = *(bf16x8*)&As[i*8];
}

// ---------------------------------------------------------------------------
// Kernel 2: causal flash attention, paired q-tiles (qlo=pid, qhi=31-pid),
// double-buffered DMA, SHARED kb AND vb fragment loads across strips
// (LDS reads per strip: 18 b128 vs 34 unpaired -> attn is LDS-BW-bound).
// Separate per-strip P buffers so PV fuses over one vb load. grid 512,
// 2 blocks/CU (reg-bound), LDS 80KB.
// ---------------------------------------------------------------------------
__global__ __launch_bounds__(256, 2) void attn_kernel(
    const short* __restrict__ Qw, const short* __restrict__ Kw,
    const short* __restrict__ Vw, short* __restrict__ attnw)
{
  __shared__ __align__(16) short Ks[2][8192];
  __shared__ __align__(16) short Vs[2][8192];
  __shared__ __align__(16) short Ps[8192];        // [strip][wave][16][64]

  const int tid = threadIdx.x;
  const int id = (int)blockIdx.x;                 // 512 blocks
  const int bh = (id & 7) | (((id >> 3) & 3) << 3);
  const int b = bh >> 3, h = bh & 7;
  const int m = id >> 5;                          // 0..15
  const int pid = (((m >> 3) ^ (id & 1)) ? 15 - (m & 7) : (m & 7));
  const int qlo = pid, qhi = 31 - pid;
  const int w = tid >> 6, lane = tid & 63, quad = lane >> 4, l16 = lane & 15;
  const int rowL = qlo*64 + w*16, rowH = qhi*64 + w*16;

  const short* Qp = Qw + (size_t)bh * 262144;     // swizzled tiles
  const short* Kp = Kw + (size_t)bh * 262144;
  const short* Vp = Vw + (size_t)bh * 262144;
  short* PwH = &Ps[w*1024];
  short* PwL = &Ps[4096 + w*1024];
  const int so = w*2048 + lane*8;

  // Q fragments for both strips (tile-swizzled layout)
  bf16x8 qaL[4], qaH[4];
  {
    const int tlL = (rowL & 63) + l16, tiL = rowL >> 6;
    const int tlH = (rowH & 63) + l16, tiH = rowH >> 6;
    #pragma unroll
    for (int kk = 0; kk < 4; kk++) {
      qaL[kk] = *(const bf16x8*)(Qp + ((size_t)tiL << 13) + tlL*128 +
                                 (((kk*4 + quad) ^ (tlL & 15)) << 3));
      qaH[kk] = *(const bf16x8*)(Qp + ((size_t)tiH << 13) + tlH*128 +
                                 (((kk*4 + quad) ^ (tlH & 15)) << 3));
    }
  }

  f32x4 oL[8], oH[8];
  #pragma unroll
  for (int e = 0; e < 8; e++) { oL[e] = (f32x4){0,0,0,0}; oH[e] = (f32x4){0,0,0,0}; }
  float lL[4] = {0,0,0,0}, lH[4] = {0,0,0,0};

  {                                               // prologue: tile 0 -> buf 0
    #pragma unroll
    for (int cc = 0; cc < 4; cc++) {
      gld16(Kp + so + cc*512, &Ks[0][w*2048 + cc*512]);
      gld16(Vp + so + cc*512, &Vs[0][w*2048 + cc*512]);
    }
  }
  int buf = 0;
  const int nIt = qhi + 1;

  for (int it = 0; it < nIt; ++it) {
    __syncthreads();                              // publish buf (vmcnt drain)
    if (it + 1 < nIt) {                           // prefetch next into buf^1
      const short* kt = Kp + ((size_t)(it+1) << 13);
      const short* vt = Vp + ((size_t)(it+1) << 13);
      #pragma unroll
      for (int cc = 0; cc < 4; cc++) {
        gld16(kt + so + cc*512, &Ks[buf^1][w*2048 + cc*512]);
        gld16(vt + so + cc*512, &Vs[buf^1][w*2048 + cc*512]);
      }
    }
    const short* ks = &Ks[buf][0];
    const short* vs = &Vs[buf][0];
    const bool doL = (it <= qlo);

    // QK^T both strips, kb loaded once
    f32x4 sH[4], sL[4];
    #pragma unroll
    for (int nj = 0; nj < 4; nj++) { sH[nj] = (f32x4){0,0,0,0}; sL[nj] = (f32x4){0,0,0,0}; }
    #pragma unroll
    for (int kk = 0; kk < 4; kk++) {
      const int swz = ((kk*4 + quad) ^ l16) << 3;
      #pragma unroll
      for (int nj = 0; nj < 4; nj++) {
        bf16x8 kb = *(const bf16x8*)&ks[(nj*16 + l16)*128 + swz];
        sH[nj] = __builtin_amdgcn_mfma_f32_16x16x32_bf16(qaH[kk], kb, sH[nj], 0, 0, 0);
        if (doL)
          sL[nj] = __builtin_amdgcn_mfma_f32_16x16x32_bf16(qaL[kk], kb, sL[nj], 0, 0, 0);
      }
    }

    // softmax H -> PwH
    {
      const int s0 = it * 64;
      const bool diag = (it == qhi);
      #pragma unroll
      for (int nj = 0; nj < 4; nj++) {
        const int key = s0 + nj*16 + l16;
        #pragma unroll
        for (int r = 0; r < 4; r++) {
          float p = EXP2F(sH[nj][r]);
          if (diag) p = (key > rowH + quad*4 + r) ? 0.f : p;
          lH[r] += p;
          const int row = quad*4 + r, col = nj*16 + l16;
          PwH[row*64 + (((col >> 3) ^ (row & 7)) << 3) + (col & 7)] = f2bf(p);
        }
      }
    }
    // softmax L -> PwL
    if (doL) {
      const int s0 = it * 64;
      const bool diag = (it == qlo);
      #pragma unroll
      for (int nj = 0; nj < 4; nj++) {
        const int key = s0 + nj*16 + l16;
        #pragma unroll
        for (int r = 0; r < 4; r++) {
          float p = EXP2F(sL[nj][r]);
          if (diag) p = (key > rowL + quad*4 + r) ? 0.f : p;
          lL[r] += p;
          const int row = quad*4 + r, col = nj*16 + l16;
          PwL[row*64 + (((col >> 3) ^ (row & 7)) << 3) + (col & 7)] = f2bf(p);
        }
      }
    }

    // PV fused: one vb load feeds both strips
    #pragma unroll
    for (int kk2 = 0; kk2 < 2; kk2++) {
      const int swz = ((kk2*4 + quad) ^ (l16 & 7)) << 3;
      bf16x8 paH = *(bf16x8*)&PwH[l16*64 + swz];
      bf16x8 paL;
      if (doL) paL = *(bf16x8*)&PwL[l16*64 + swz];
      #pragma unroll
      for (int e = 0; e < 8; e++) {
        bf16x8 vb = *(const bf16x8*)&vs[(e*16 + l16)*64 + swz];
        oH[e] = __builtin_amdgcn_mfma_f32_16x16x32_bf16(paH, vb, oH[e], 0, 0, 0);
        if (doL)
          oL[e] = __builtin_amdgcn_mfma_f32_16x16x32_bf16(paL, vb, oL[e], 0, 0, 0);
      }
    }
    buf ^= 1;
  }

  // epilogue: l-reduce, build LDS images (reuse Ks, 32KB), b128 copy-out
  #pragma unroll
  for (int r = 0; r < 4; r++) {
    float tL = lL[r], tH = lH[r];
    tL += __shfl_xor(tL, 1); tL += __shfl_xor(tL, 2);
    tL += __shfl_xor(tL, 4); tL += __shfl_xor(tL, 8);
    tH += __shfl_xor(tH, 1); tH += __shfl_xor(tH, 2);
    tH += __shfl_xor(tH, 4); tH += __shfl_xor(tH, 8);
    lL[r] = 1.0f / tL; lH[r] = 1.0f / tH;
  }
  __syncthreads();                                // done reading Ks/Vs
  short* img = &Ks[0][0];                         // 16384 shorts
  #pragma unroll
  for (int e = 0; e < 8; e++) {
    const int c = e*2 + (l16 >> 3);
    #pragma unroll
    for (int r = 0; r < 4; r++) {
      const int lrow = w*16 + quad*4 + r;         // 0..63 within strip
      const int sub = lrow >> 5, r32 = lrow & 31;
      const int off = sub*4096 + r32*128 + ((c ^ (r32 & 15)) << 3) + (l16 & 7);
      img[off]        = f2bf(oL[e][r] * lL[r]);
      img[8192 + off] = f2bf(oH[e][r] * lH[r]);
    }
  }
  __syncthreads();
  const int stL = b*64 + qlo*2, stH = b*64 + qhi*2;
  #pragma unroll
  for (int seg = 0; seg < 4; seg++) {
    const int st = ((seg < 2) ? stL : stH) + (seg & 1);
    short* dst = attnw + ((size_t)st*8 + h)*4096;
    const short* src = img + seg*4096;
    #pragma unroll
    for (int i = tid; i < 512; i += 256)
      *(bf16x8*)&dst[i*8] = *(const bf16x8*)&src[i*8];
  }
}

// ---------------------------------------------------------------------------
// Kernel 3: Wu(1024x128 f32) -> WuT tile images (8 x 128n x 128k, swizzled).
// ---------------------------------------------------------------------------
__global__ __launch_bounds__(256) void wu_prep(
    const float* __restrict__ Wu, short* __restrict__ WuT)
{
  __shared__ __align__(16) short Tt[128*128];
  const int tid = threadIdx.x;
  const int kc = blockIdx.x;
  #pragma unroll 4
  for (int i = tid; i < 4096; i += 256) {
    int kl = i >> 5, n4 = (i & 31) << 2;
    float4 v = *(const float4*)&Wu[(size_t)(kc*128 + kl) * D_ + n4];
    float vv[4] = {v.x, v.y, v.z, v.w};
    #pragma unroll
    for (int j = 0; j < 4; j++) {
      int n = n4 + j;
      Tt[n*128 + (((kl >> 3) ^ (n & 15)) << 3) + (kl & 7)] = f2bf(vv[j]);
    }
  }
  __syncthreads();
  short* dst = WuT + (size_t)kc * 16384;
  #pragma unroll 2
  for (int i = tid; i < 2048; i += 256)
    *(bf16x8*)&dst[i*8] = *(bf16x8*)&Tt[i*8];
}

// ---------------------------------------------------------------------------
// Kernel 4: out = attn @ Wu + bu -> fp32. DMA-staged, double-buffered over
// 8 k-chunks, fused bias. grid 512 (m-tile 16), 2 blocks/CU.
// ---------------------------------------------------------------------------
__global__ __launch_bounds__(256, 2) void out_proj(
    const short* __restrict__ attnw, const short* __restrict__ WuT,
    const float* __restrict__ bu, float* __restrict__ out)
{
  __shared__ __align__(16) short As2[2][2048];
  __shared__ __align__(16) short Bs2[2][16384];
  const int tid = threadIdx.x;
  const int w = tid >> 6, lane = tid & 63, quad = lane >> 4, l16 = lane & 15;
  const int m0 = (int)blockIdx.x * 16;
  const int mtile32 = m0 >> 5, half = (m0 >> 4) & 1;

  f32x4 o2[2];
  o2[0] = (f32x4){0,0,0,0}; o2[1] = (f32x4){0,0,0,0};

  {
    const short* ab = attnw + (size_t)(mtile32*8)*4096 + half*2048;
    gld16(ab + w*512 + lane*8, &As2[0][w*512]);
    #pragma unroll
    for (int cc = 0; cc < 8; cc++)
      gld16(WuT + w*4096 + cc*512 + lane*8, &Bs2[0][w*4096 + cc*512]);
  }
  int buf = 0;

  for (int kc = 0; kc < 8; kc++) {
    __syncthreads();
    if (kc < 7) {
      const short* ab = attnw + (size_t)(mtile32*8 + kc + 1)*4096 + half*2048;
      const short* bb = WuT + (size_t)(kc + 1)*16384;
      gld16(ab + w*512 + lane*8, &As2[buf^1][w*512]);
      #pragma unroll
      for (int cc = 0; cc < 8; cc++)
        gld16(bb + w*4096 + cc*512 + lane*8, &Bs2[buf^1][w*4096 + cc*512]);
    }
    const short* as = &As2[buf][0];
    const short* bs = &Bs2[buf][0];
    #pragma unroll
    for (int kk = 0; kk < 4; kk++) {
      const int swz = ((kk*4 + quad) ^ l16) << 3;
      bf16x8 a = *(const bf16x8*)&as[l16*128 + swz];
      #pragma unroll
      for (int e = 0; e < 2; e++) {
        bf16x8 bfr = *(const bf16x8*)&bs[((w*2 + e)*16 + l16)*128 + swz];
        o2[e] = __builtin_amdgcn_mfma_f32_16x16x32_bf16(a, bfr, o2[e], 0, 0, 0);
      }
    }
    buf ^= 1;
  }

  #pragma unroll
  for (int e = 0; e < 2; e++) {
    const int n = (w*2 + e)*16 + l16;
    const float bias = bu[n];
    #pragma unroll
    for (int r = 0; r < 4; r++) {
      const int mm = m0 + quad*4 + r;
      out[(size_t)mm*D_ + n] = o2[e][r] + bias;
    }
  }
}

extern "C" void kernel_launch(void* const* d_in, const int* in_sizes, int n_in,
                              void* d_out, int out_size, void* d_ws, size_t ws_size,
                              hipStream_t stream) {
  (void)in_sizes; (void)n_in; (void)out_size; (void)ws_size;
  const float* x  = (const float*)d_in[0];
  const float* Wq = (const float*)d_in[1];
  const float* Wk = (const float*)d_in[2];
  const float* Wv = (const float*)d_in[3];
  const float* Wu = (const float*)d_in[4];
  const float* bu = (const float*)d_in[5];
  float* out = (float*)d_out;

  const size_t headElems = (size_t)B_ * H_ * T_ * D_;   // 8,388,608
  short* Qw    = (short*)d_ws;
  short* Kw    = Qw + headElems;
  short* Vw    = Kw + headElems;
  short* attnw = Vw + headElems;                        // 16 MB (tiled images)
  short* xbf = attnw;                                   // prep outputs live in
  short* WT  = attnw + 1048576;                         // not-yet-written attnw
  short* WuT = Kw;                                      // Kw dead after attn

  prep<<<dim3(88), 256, 0, stream>>>(x, Wq, Wk, Wv, xbf, WT);
  qkv_proj<<<dim3(64, 24), 256, 0, stream>>>(xbf, WT, Qw, Kw, Vw);
  attn_kernel<<<dim3(512), 256, 0, stream>>>(Qw, Kw, Vw, attnw);
  wu_prep<<<dim3(8), 256, 0, stream>>>(Wu, WuT);
  out_proj<<<dim3(512), 256, 0, stream>>>(attnw, WuT, bu, out);
}

// Round 9
// 190.755 us; speedup vs baseline: 1.0080x; 1.0080x over previous
//
#include <hip/hip_runtime.h>
#include <hip/hip_bf16.h>
#include <math.h>

#define B_ 4
#define T_ 2048
#define D_ 128
#define H_ 8
#define BT_ 8192
#define HD_ 1024

typedef __attribute__((ext_vector_type(8))) short bf16x8;
typedef __attribute__((ext_vector_type(4))) float f32x4;
typedef __attribute__((ext_vector_type(16))) float f32x16;

__device__ __forceinline__ short f2bf(float f) {
  union { float f; unsigned u; } v; v.f = f;
  return (short)((v.u + 0x8000u) >> 16);
}

#if __has_builtin(__builtin_amdgcn_exp2f)
#define EXP2F(x) __builtin_amdgcn_exp2f(x)
#else
#define EXP2F(x) exp2f(x)
#endif

#define QSCALE 0.12752040242046492f   // k^-0.5 * log2(e), folded into Q
#define VSCALE 0.29730177875068026f   // k^-0.25, folded into V

// async global->LDS DMA, 16B/lane; LDS dest = wave-uniform base + lane*16
__device__ __forceinline__ void gld16(const short* g, short* l) {
  __builtin_amdgcn_global_load_lds(
      (const __attribute__((address_space(1))) void*)g,
      (__attribute__((address_space(3))) void*)l, 16, 0, 0);
}

// ---------------------------------------------------------------------------
// Kernel 0: prep. blocks 0..23: Wq/Wk/Wv -> WT swizzled tile images.
// blocks 24..87: x -> xbf swizzled tile images.
// ---------------------------------------------------------------------------
__global__ __launch_bounds__(256) void prep(
    const float* __restrict__ x, const float* __restrict__ Wq,
    const float* __restrict__ Wk, const float* __restrict__ Wv,
    short* __restrict__ xbf, short* __restrict__ WT)
{
  __shared__ __align__(16) short Tt[128*128];
  const int tid = threadIdx.x;
  const int id = blockIdx.x;
  if (id < 24) {
    const int wsel = id >> 3, nt = id & 7;
    const float* W = (wsel == 0) ? Wq : (wsel == 1) ? Wk : Wv;
    #pragma unroll 4
    for (int i = tid; i < 4096; i += 256) {
      int k = i >> 5, n4 = (i & 31) << 2;
      float4 v = *(const float4*)&W[(size_t)k * HD_ + nt*128 + n4];
      float vv[4] = {v.x, v.y, v.z, v.w};
      #pragma unroll
      for (int j = 0; j < 4; j++) {
        int n = n4 + j;
        Tt[n*128 + (((k >> 3) ^ (n & 15)) << 3) + (k & 7)] = f2bf(vv[j]);
      }
    }
    __syncthreads();
    short* dst = WT + (size_t)id * 16384;
    #pragma unroll 2
    for (int i = tid; i < 2048; i += 256)
      *(bf16x8*)&dst[i*8] = *(bf16x8*)&Tt[i*8];
  } else {
    const int xb = id - 24;                       // 64 tiles
    const float* xs = x + (size_t)xb * 16384;
    short* dst = xbf + (size_t)xb * 16384;
    #pragma unroll 4
    for (int i = tid; i < 4096; i += 256) {
      float4 v = ((const float4*)xs)[i];
      int row = i >> 5, c = (i & 31) >> 1, half = i & 1;
      short4 p;
      p.x = f2bf(v.x); p.y = f2bf(v.y); p.z = f2bf(v.z); p.w = f2bf(v.w);
      *(short4*)&dst[(row*16 + (c ^ (row & 15)))*8 + half*4] = p;
    }
  }
}

// ---------------------------------------------------------------------------
// Kernel 1: QKV GEMM, fully DMA-staged. grid (64 m, 24 n=wsel*8+head).
// Q AND K stored as pre-swizzled 16KB tiles (64t x 128d); V transposed
// tiles (128d x 64t). Epilogue: LDS image + linear 32KB b128 copy-out.
// ---------------------------------------------------------------------------
__global__ __launch_bounds__(256, 2) void qkv_proj(
    const short* __restrict__ xbf, const short* __restrict__ WT,
    short* __restrict__ Qw, short* __restrict__ Kw, short* __restrict__ Vw)
{
  __shared__ __align__(16) short As[16384];
  __shared__ __align__(16) short Bs[16384];
  const int tid = threadIdx.x;
  const int w = tid >> 6, lane = tid & 63, quad = lane >> 4, l16 = lane & 15;
  const int m0 = blockIdx.x * 128;

  {
    const short* asrc = xbf + (size_t)blockIdx.x * 16384;
    const short* bsrc = WT + (size_t)blockIdx.y * 16384;
    const int so = w*4096 + lane*8;
    #pragma unroll
    for (int cc = 0; cc < 8; cc++) {
      gld16(asrc + so + cc*512, &As[w*4096 + cc*512]);
      gld16(bsrc + so + cc*512, &Bs[w*4096 + cc*512]);
    }
  }
  __syncthreads();

  const int wm = (w & 1) * 64, wn = (w >> 1) * 64;
  f32x4 acc[4][4];
  #pragma unroll
  for (int a = 0; a < 4; a++)
    #pragma unroll
    for (int b = 0; b < 4; b++) acc[a][b] = (f32x4){0.f, 0.f, 0.f, 0.f};

  #pragma unroll
  for (int kk = 0; kk < 4; kk++) {
    const int swz = ((kk*4 + quad) ^ l16) << 3;
    bf16x8 af[4], bfv[4];
    #pragma unroll
    for (int mi = 0; mi < 4; mi++) af[mi]  = *(bf16x8*)&As[(wm + mi*16 + l16)*128 + swz];
    #pragma unroll
    for (int ni = 0; ni < 4; ni++) bfv[ni] = *(bf16x8*)&Bs[(wn + ni*16 + l16)*128 + swz];
    #pragma unroll
    for (int mi = 0; mi < 4; mi++)
      #pragma unroll
      for (int ni = 0; ni < 4; ni++)
        acc[mi][ni] = __builtin_amdgcn_mfma_f32_16x16x32_bf16(af[mi], bfv[ni], acc[mi][ni], 0, 0, 0);
  }

  __syncthreads();     // all MFMA reads of As/Bs done; reuse As as image
  const int wsel = (int)blockIdx.y >> 3;
  #pragma unroll
  for (int mi = 0; mi < 4; mi++) {
    #pragma unroll
    for (int ni = 0; ni < 4; ni++) {
      const int t0l = wm + mi*16 + quad*4;        // local t rows t0l..t0l+3
      const int d   = wn + ni*16 + l16;           // local d
      if (wsel <= 1) {                            // Q and K: same tile swizzle
        const float sc = wsel ? 1.0f : QSCALE;
        const int c = d >> 3;
        #pragma unroll
        for (int r = 0; r < 4; r++) {
          const int tl = (t0l + r) & 63, tile = (t0l + r) >> 6;
          As[tile*8192 + tl*128 + ((c ^ (tl & 15)) << 3) + (d & 7)] =
              f2bf(acc[mi][ni][r] * sc);
        }
      } else {                                    // V: transposed tile
        #pragma unroll
        for (int r = 0; r < 4; r++) {
          const int tl = (t0l + r) & 63, tile = (t0l + r) >> 6;
          As[tile*8192 + d*64 + (((tl >> 3) ^ (d & 7)) << 3) + (tl & 7)] =
              f2bf(acc[mi][ni][r] * VSCALE);
        }
      }
    }
  }
  __syncthreads();

  const int h = (int)blockIdx.y & 7;
  const int b = m0 >> 11, t0 = m0 & 2047;
  short* base = ((wsel == 0) ? Qw : (wsel == 1) ? Kw : Vw)
              + (size_t)(b*H_ + h)*262144 + (size_t)t0*128;
  #pragma unroll 2
  for (int i = tid; i < 2048; i += 256)
    *(bf16x8*)&base[i*8] = *(bf16x8*)&As[i*8];
}

// ---------------------------------------------------------------------------
// Kernel 2: causal flash attention on 32x32x16 MFMA. q-tile 128/block (one
// 32-row strip per wave), k-tile 64, double-buffered DMA. LDS reads per unit
// work HALVED vs 16x16 path (16 kb + 16 vb + 4 pa b128 per 2x work-unit).
// grid 512 = 16 qt x 32 bh; 2 blocks/CU; co-resident pairs sum to 34 iters.
// Waves fully below the diagonal skip compute. LDS 80 KB.
// ---------------------------------------------------------------------------
__global__ __launch_bounds__(256, 2) void attn_kernel(
    const short* __restrict__ Qw, const short* __restrict__ Kw,
    const short* __restrict__ Vw, short* __restrict__ attnw)
{
  __shared__ __align__(16) short Ks[2][8192];
  __shared__ __align__(16) short Vs[2][8192];
  __shared__ __align__(16) short Ps[8192];        // 4 waves x 32x64 P

  const int tid = threadIdx.x;
  const int id = (int)blockIdx.x;                 // 512 blocks
  const int bh = (id & 7) | (((id >> 3) & 3) << 3);
  const int b = bh >> 3, h = bh & 7;
  const int m = id >> 5;                          // 0..15
  const int qt = (((m >> 3) ^ (id & 1)) ? 15 - (m & 7) : (m & 7));
  const int w = tid >> 6, lane = tid & 63;
  const int l32 = lane & 31, hlf = lane >> 5;
  const int rowW = qt*128 + w*32;                 // wave's first q row

  const short* Qp = Qw + (size_t)bh * 262144;     // swizzled 16KB tiles
  const short* Kp = Kw + (size_t)bh * 262144;
  const short* Vp = Vw + (size_t)bh * 262144;
  short* Pw = &Ps[w*2048];
  const int so = w*2048 + lane*8;

  // Q A-fragments: m = l32, k = kk*16 + hlf*8 + j (slot-permutation safe)
  bf16x8 qa[8];
  {
    const int grow = rowW + l32;
    const int ti = grow >> 6, tl = grow & 63;
    const short* qp = Qp + ((size_t)ti << 13) + tl*128;
    #pragma unroll
    for (int kk = 0; kk < 8; kk++)
      qa[kk] = *(const bf16x8*)(qp + (((kk*2 + hlf) ^ (tl & 15)) << 3));
  }

  f32x16 o[4];
  float l[16];
  #pragma unroll
  for (int nt = 0; nt < 4; nt++)
    #pragma unroll
    for (int r = 0; r < 16; r++) o[nt][r] = 0.f;
  #pragma unroll
  for (int r = 0; r < 16; r++) l[r] = 0.f;

  #pragma unroll
  for (int cc = 0; cc < 4; cc++) {                // prologue: tile 0 -> buf 0
    gld16(Kp + so + cc*512, &Ks[0][w*2048 + cc*512]);
    gld16(Vp + so + cc*512, &Vs[0][w*2048 + cc*512]);
  }
  int buf = 0;
  const int nIt = 2*qt + 2;

  for (int it = 0; it < nIt; ++it) {
    __syncthreads();                              // publish buf (vmcnt drain)
    if (it + 1 < nIt) {                           // prefetch next into buf^1
      const short* kt = Kp + ((size_t)(it+1) << 13);
      const short* vt = Vp + ((size_t)(it+1) << 13);
      #pragma unroll
      for (int cc = 0; cc < 4; cc++) {
        gld16(kt + so + cc*512, &Ks[buf^1][w*2048 + cc*512]);
        gld16(vt + so + cc*512, &Vs[buf^1][w*2048 + cc*512]);
      }
    }
    const int s0 = it * 64;
    if (s0 <= rowW + 31) {                        // else fully masked: skip
      const short* ks = &Ks[buf][0];
      const short* vs = &Vs[buf][0];

      // S = Q K^T : 32 x 64 per wave, 16 MFMA
      f32x16 s[2];
      #pragma unroll
      for (int nj = 0; nj < 2; nj++)
        #pragma unroll
        for (int r = 0; r < 16; r++) s[nj][r] = 0.f;
      #pragma unroll
      for (int kk = 0; kk < 8; kk++) {
        #pragma unroll
        for (int nj = 0; nj < 2; nj++) {
          const int srow = nj*32 + l32;
          bf16x8 kb = *(const bf16x8*)&ks[srow*128 + (((kk*2 + hlf) ^ (srow & 15)) << 3)];
          s[nj] = __builtin_amdgcn_mfma_f32_32x32x16_bf16(qa[kk], kb, s[nj], 0, 0, 0);
        }
      }

      // softmax (fixed-max exp2 domain); C row = (r&3)+8*(r>>2)+4*hlf
      const bool diag = (s0 + 63 > rowW);
      #pragma unroll
      for (int nj = 0; nj < 2; nj++) {
        const int col = nj*32 + l32;
        const int key = s0 + col;
        #pragma unroll
        for (int r = 0; r < 16; r++) {
          const int rl = (r & 3) + 8*(r >> 2) + 4*hlf;
          float p = EXP2F(s[nj][r]);
          if (diag) p = (key > rowW + rl) ? 0.f : p;
          l[r] += p;
          Pw[rl*64 + (((col >> 3) ^ (rl & 7)) << 3) + (col & 7)] = f2bf(p);
        }
      }

      // O += P V : 32 x 128 per wave, 16 MFMA, 4 pa + 16 vb loads
      #pragma unroll
      for (int kk2 = 0; kk2 < 4; kk2++) {
        bf16x8 pa = *(const bf16x8*)&Pw[l32*64 + (((kk2*2 + hlf) ^ (l32 & 7)) << 3)];
        #pragma unroll
        for (int nt = 0; nt < 4; nt++) {
          const int e = nt*32 + l32;
          bf16x8 vb = *(const bf16x8*)&vs[e*64 + (((kk2*2 + hlf) ^ (e & 7)) << 3)];
          o[nt] = __builtin_amdgcn_mfma_f32_32x32x16_bf16(pa, vb, o[nt], 0, 0, 0);
        }
      }
    }
    buf ^= 1;
  }

  // epilogue: l-reduce across the 32 lanes holding each row
  #pragma unroll
  for (int r = 0; r < 16; r++) {
    float t = l[r];
    t += __shfl_xor(t, 1); t += __shfl_xor(t, 2); t += __shfl_xor(t, 4);
    t += __shfl_xor(t, 8); t += __shfl_xor(t, 16);
    l[r] = 1.0f / t;
  }
  __syncthreads();                                // done with Ks/Vs
  short* img = &Ks[0][0];                         // 16384 shorts = 128x128
  #pragma unroll
  for (int nt = 0; nt < 4; nt++) {
    #pragma unroll
    for (int r = 0; r < 16; r++) {
      const int rl = (r & 3) + 8*(r >> 2) + 4*hlf; // 0..31, sub-tile = w
      const int d = nt*32 + l32;
      img[w*4096 + rl*128 + (((d >> 3) ^ (rl & 15)) << 3) + (d & 7)] =
          f2bf(o[nt][r] * l[r]);
    }
  }
  __syncthreads();
  const int st0 = b*64 + qt*4;
  #pragma unroll
  for (int i = tid; i < 2048; i += 256) {
    const int sub = i >> 9, rem = i & 511;
    short* dst = attnw + ((size_t)(st0 + sub)*8 + h)*4096 + rem*8;
    *(bf16x8*)dst = *(const bf16x8*)&img[i*8];
  }
}

// ---------------------------------------------------------------------------
// Kernel 3: Wu(1024x128 f32) -> WuT tile images (8 x 128n x 128k, swizzled).
// ---------------------------------------------------------------------------
__global__ __launch_bounds__(256) void wu_prep(
    const float* __restrict__ Wu, short* __restrict__ WuT)
{
  __shared__ __align__(16) short Tt[128*128];
  const int tid = threadIdx.x;
  const int kc = blockIdx.x;
  #pragma unroll 4
  for (int i = tid; i < 4096; i += 256) {
    int kl = i >> 5, n4 = (i & 31) << 2;
    float4 v = *(const float4*)&Wu[(size_t)(kc*128 + kl) * D_ + n4];
    float vv[4] = {v.x, v.y, v.z, v.w};
    #pragma unroll
    for (int j = 0; j < 4; j++) {
      int n = n4 + j;
      Tt[n*128 + (((kl >> 3) ^ (n & 15)) << 3) + (kl & 7)] = f2bf(vv[j]);
    }
  }
  __syncthreads();
  short* dst = WuT + (size_t)kc * 16384;
  #pragma unroll 2
  for (int i = tid; i < 2048; i += 256)
    *(bf16x8*)&dst[i*8] = *(bf16x8*)&Tt[i*8];
}

// ---------------------------------------------------------------------------
// Kernel 4: out = attn @ Wu + bu -> fp32. DMA-staged, double-buffered over
// 8 k-chunks, fused bias. grid 512 (m-tile 16), 2 blocks/CU.
// ---------------------------------------------------------------------------
__global__ __launch_bounds__(256, 2) void out_proj(
    const short* __restrict__ attnw, const short* __restrict__ WuT,
    const float* __restrict__ bu, float* __restrict__ out)
{
  __shared__ __align__(16) short As2[2][2048];
  __shared__ __align__(16) short Bs2[2][16384];
  const int tid = threadIdx.x;
  const int w = tid >> 6, lane = tid & 63, quad = lane >> 4, l16 = lane & 15;
  const int m0 = (int)blockIdx.x * 16;
  const int mtile32 = m0 >> 5, half = (m0 >> 4) & 1;

  f32x4 o2[2];
  o2[0] = (f32x4){0,0,0,0}; o2[1] = (f32x4){0,0,0,0};

  {
    const short* ab = attnw + (size_t)(mtile32*8)*4096 + half*2048;
    gld16(ab + w*512 + lane*8, &As2[0][w*512]);
    #pragma unroll
    for (int cc = 0; cc < 8; cc++)
      gld16(WuT + w*4096 + cc*512 + lane*8, &Bs2[0][w*4096 + cc*512]);
  }
  int buf = 0;

  for (int kc = 0; kc < 8; kc++) {
    __syncthreads();
    if (kc < 7) {
      const short* ab = attnw + (size_t)(mtile32*8 + kc + 1)*4096 + half*2048;
      const short* bb = WuT + (size_t)(kc + 1)*16384;
      gld16(ab + w*512 + lane*8, &As2[buf^1][w*512]);
      #pragma unroll
      for (int cc = 0; cc < 8; cc++)
        gld16(bb + w*4096 + cc*512 + lane*8, &Bs2[buf^1][w*4096 + cc*512]);
    }
    const short* as = &As2[buf][0];
    const short* bs = &Bs2[buf][0];
    #pragma unroll
    for (int kk = 0; kk < 4; kk++) {
      const int swz = ((kk*4 + quad) ^ l16) << 3;
      bf16x8 a = *(const bf16x8*)&as[l16*128 + swz];
      #pragma unroll
      for (int e = 0; e < 2; e++) {
        bf16x8 bfr = *(const bf16x8*)&bs[((w*2 + e)*16 + l16)*128 + swz];
        o2[e] = __builtin_amdgcn_mfma_f32_16x16x32_bf16(a, bfr, o2[e], 0, 0, 0);
      }
    }
    buf ^= 1;
  }

  #pragma unroll
  for (int e = 0; e < 2; e++) {
    const int n = (w*2 + e)*16 + l16;
    const float bias = bu[n];
    #pragma unroll
    for (int r = 0; r < 4; r++) {
      const int mm = m0 + quad*4 + r;
      out[(size_t)mm*D_ + n] = o2[e][r] + bias;
    }
  }
}

extern "C" void kernel_launch(void* const* d_in, const int* in_sizes, int n_in,
                              void* d_out, int out_size, void* d_ws, size_t ws_size,
                              hipStream_t stream) {
  (void)in_sizes; (void)n_in; (void)out_size; (void)ws_size;
  const float* x  = (const float*)d_in[0];
  const float* Wq = (const float*)d_in[1];
  const float* Wk = (const float*)d_in[2];
  const float* Wv = (const float*)d_in[3];
  const float* Wu = (const float*)d_in[4];
  const float* bu = (const float*)d_in[5];
  float* out = (float*)d_out;

  const size_t headElems = (size_t)B_ * H_ * T_ * D_;   // 8,388,608
  short* Qw    = (short*)d_ws;
  short* Kw    = Qw + headElems;
  short* Vw    = Kw + headElems;
  short* attnw = Vw + headElems;                        // 16 MB (tiled images)
  short* xbf = attnw;                                   // prep outputs live in
  short* WT  = attnw + 1048576;                         // not-yet-written attnw
  short* WuT = Kw;                                      // Kw dead after attn

  prep<<<dim3(88), 256, 0, stream>>>(x, Wq, Wk, Wv, xbf, WT);
  qkv_proj<<<dim3(64, 24), 256, 0, stream>>>(xbf, WT, Qw, Kw, Vw);
  attn_kernel<<<dim3(512), 256, 0, stream>>>(Qw, Kw, Vw, attnw);
  wu_prep<<<dim3(8), 256, 0, stream>>>(Wu, WuT);
  out_proj<<<dim3(512), 256, 0, stream>>>(attnw, WuT, bu, out);
}

// Round 10
// 166.454 us; speedup vs baseline: 1.1552x; 1.1460x over previous
//
#include <hip/hip_runtime.h>
#include <hip/hip_bf16.h>
#include <math.h>

#define B_ 4
#define T_ 2048
#define D_ 128
#define H_ 8
#define BT_ 8192
#define HD_ 1024

typedef __attribute__((ext_vector_type(8))) short bf16x8;
typedef __attribute__((ext_vector_type(4))) float f32x4;

__device__ __forceinline__ short f2bf(float f) {
  union { float f; unsigned u; } v; v.f = f;
  return (short)((v.u + 0x8000u) >> 16);
}

#if __has_builtin(__builtin_amdgcn_exp2f)
#define EXP2F(x) __builtin_amdgcn_exp2f(x)
#else
#define EXP2F(x) exp2f(x)
#endif

#define QSCALE 0.12752040242046492f   // k^-0.5 * log2(e), folded into Q
#define VSCALE 0.29730177875068026f   // k^-0.25, folded into V

// async global->LDS DMA, 16B/lane; LDS dest = wave-uniform base + lane*16
__device__ __forceinline__ void gld16(const short* g, short* l) {
  __builtin_amdgcn_global_load_lds(
      (const __attribute__((address_space(1))) void*)g,
      (__attribute__((address_space(3))) void*)l, 16, 0, 0);
}

// ---------------------------------------------------------------------------
// Kernel 0: prep. blocks 0..23: Wq/Wk/Wv -> WT swizzled tile images.
// blocks 24..87: x -> xbf swizzled tile images.
// ---------------------------------------------------------------------------
__global__ __launch_bounds__(256) void prep(
    const float* __restrict__ x, const float* __restrict__ Wq,
    const float* __restrict__ Wk, const float* __restrict__ Wv,
    short* __restrict__ xbf, short* __restrict__ WT)
{
  __shared__ __align__(16) short Tt[128*128];
  const int tid = threadIdx.x;
  const int id = blockIdx.x;
  if (id < 24) {
    const int wsel = id >> 3, nt = id & 7;
    const float* W = (wsel == 0) ? Wq : (wsel == 1) ? Wk : Wv;
    #pragma unroll 4
    for (int i = tid; i < 4096; i += 256) {
      int k = i >> 5, n4 = (i & 31) << 2;
      float4 v = *(const float4*)&W[(size_t)k * HD_ + nt*128 + n4];
      float vv[4] = {v.x, v.y, v.z, v.w};
      #pragma unroll
      for (int j = 0; j < 4; j++) {
        int n = n4 + j;
        Tt[n*128 + (((k >> 3) ^ (n & 15)) << 3) + (k & 7)] = f2bf(vv[j]);
      }
    }
    __syncthreads();
    short* dst = WT + (size_t)id * 16384;
    #pragma unroll 2
    for (int i = tid; i < 2048; i += 256)
      *(bf16x8*)&dst[i*8] = *(bf16x8*)&Tt[i*8];
  } else {
    const int xb = id - 24;                       // 64 tiles
    const float* xs = x + (size_t)xb * 16384;
    short* dst = xbf + (size_t)xb * 16384;
    #pragma unroll 4
    for (int i = tid; i < 4096; i += 256) {
      float4 v = ((const float4*)xs)[i];
      int row = i >> 5, c = (i & 31) >> 1, half = i & 1;
      short4 p;
      p.x = f2bf(v.x); p.y = f2bf(v.y); p.z = f2bf(v.z); p.w = f2bf(v.w);
      *(short4*)&dst[(row*16 + (c ^ (row & 15)))*8 + half*4] = p;
    }
  }
}

// ---------------------------------------------------------------------------
// Kernel 1: QKV GEMM, fully DMA-staged. grid (64 m, 24 n=wsel*8+head).
// Q AND K stored as pre-swizzled 16KB tiles (64t x 128d); V transposed
// tiles (128d x 64t). Epilogue: LDS image + linear 32KB b128 copy-out.
// ---------------------------------------------------------------------------
__global__ __launch_bounds__(256, 2) void qkv_proj(
    const short* __restrict__ xbf, const short* __restrict__ WT,
    short* __restrict__ Qw, short* __restrict__ Kw, short* __restrict__ Vw)
{
  __shared__ __align__(16) short As[16384];
  __shared__ __align__(16) short Bs[16384];
  const int tid = threadIdx.x;
  const int w = tid >> 6, lane = tid & 63, quad = lane >> 4, l16 = lane & 15;
  const int m0 = blockIdx.x * 128;

  {
    const short* asrc = xbf + (size_t)blockIdx.x * 16384;
    const short* bsrc = WT + (size_t)blockIdx.y * 16384;
    const int so = w*4096 + lane*8;
    #pragma unroll
    for (int cc = 0; cc < 8; cc++) {
      gld16(asrc + so + cc*512, &As[w*4096 + cc*512]);
      gld16(bsrc + so + cc*512, &Bs[w*4096 + cc*512]);
    }
  }
  __syncthreads();

  const int wm = (w & 1) * 64, wn = (w >> 1) * 64;
  f32x4 acc[4][4];
  #pragma unroll
  for (int a = 0; a < 4; a++)
    #pragma unroll
    for (int b = 0; b < 4; b++) acc[a][b] = (f32x4){0.f, 0.f, 0.f, 0.f};

  #pragma unroll
  for (int kk = 0; kk < 4; kk++) {
    const int swz = ((kk*4 + quad) ^ l16) << 3;
    bf16x8 af[4], bfv[4];
    #pragma unroll
    for (int mi = 0; mi < 4; mi++) af[mi]  = *(bf16x8*)&As[(wm + mi*16 + l16)*128 + swz];
    #pragma unroll
    for (int ni = 0; ni < 4; ni++) bfv[ni] = *(bf16x8*)&Bs[(wn + ni*16 + l16)*128 + swz];
    #pragma unroll
    for (int mi = 0; mi < 4; mi++)
      #pragma unroll
      for (int ni = 0; ni < 4; ni++)
        acc[mi][ni] = __builtin_amdgcn_mfma_f32_16x16x32_bf16(af[mi], bfv[ni], acc[mi][ni], 0, 0, 0);
  }

  __syncthreads();     // all MFMA reads of As/Bs done; reuse As as image
  const int wsel = (int)blockIdx.y >> 3;
  #pragma unroll
  for (int mi = 0; mi < 4; mi++) {
    #pragma unroll
    for (int ni = 0; ni < 4; ni++) {
      const int t0l = wm + mi*16 + quad*4;        // local t rows t0l..t0l+3
      const int d   = wn + ni*16 + l16;           // local d
      if (wsel <= 1) {                            // Q and K: same tile swizzle
        const float sc = wsel ? 1.0f : QSCALE;
        const int c = d >> 3;
        #pragma unroll
        for (int r = 0; r < 4; r++) {
          const int tl = (t0l + r) & 63, tile = (t0l + r) >> 6;
          As[tile*8192 + tl*128 + ((c ^ (tl & 15)) << 3) + (d & 7)] =
              f2bf(acc[mi][ni][r] * sc);
        }
      } else {                                    // V: transposed tile
        #pragma unroll
        for (int r = 0; r < 4; r++) {
          const int tl = (t0l + r) & 63, tile = (t0l + r) >> 6;
          As[tile*8192 + d*64 + (((tl >> 3) ^ (d & 7)) << 3) + (tl & 7)] =
              f2bf(acc[mi][ni][r] * VSCALE);
        }
      }
    }
  }
  __syncthreads();

  const int h = (int)blockIdx.y & 7;
  const int b = m0 >> 11, t0 = m0 & 2047;
  short* base = ((wsel == 0) ? Qw : (wsel == 1) ? Kw : Vw)
              + (size_t)(b*H_ + h)*262144 + (size_t)t0*128;
  #pragma unroll 2
  for (int i = tid; i < 2048; i += 256)
    *(bf16x8*)&base[i*8] = *(bf16x8*)&As[i*8];
}

// ---------------------------------------------------------------------------
// Kernel 2: causal flash attention — r5 structure (best measured: 63.5 us).
// One 64-row q-tile per block, grid 1024 (4 blocks/CU, 16 waves/CU, 40KB
// LDS). Single-buffer DMA staging, two barriers/iter, TLP-covered latency.
// qi from slot=(j&3)^((j>>5)&3): co-resident groups of 4 sum to 66 iters.
// Epilogue: LDS image (reuse Ks) + linear b128 copy-out to tile images.
// ---------------------------------------------------------------------------
__global__ __launch_bounds__(256, 4) void attn_kernel(
    const short* __restrict__ Qw, const short* __restrict__ Kw,
    const short* __restrict__ Vw, short* __restrict__ attnw)
{
  __shared__ __align__(16) short Ks[8192];        // 64t x 128d swizzled
  __shared__ __align__(16) short Vs[8192];        // 128d x 64t swizzled
  __shared__ __align__(16) short Ps[4096];        // 4 waves x 16x64

  const int tid = threadIdx.x;
  const int id = (int)blockIdx.x;                 // 1024 blocks
  const int xcd = id & 7;
  const int j   = id >> 3;                        // 0..127 within XCD
  const int u   = j & 3;
  const int q   = (j >> 2) & 7;
  const int vv  = (j >> 5) & 3;
  const int slot = u ^ vv;
  const int qi = (slot == 0) ? q : (slot == 1) ? 15 - q
               : (slot == 2) ? 16 + q : 31 - q;
  const int bh = xcd | (u << 3);
  const int b = bh >> 3, h = bh & 7;
  const int w = tid >> 6, lane = tid & 63, quad = lane >> 4, l16 = lane & 15;
  const int rowQ = qi*64 + w*16;

  const short* Qp = Qw + (size_t)bh * 262144;     // swizzled 16KB tiles
  const short* Kp = Kw + (size_t)bh * 262144;
  const short* Vp = Vw + (size_t)bh * 262144;

  // Q A-fragments from swizzled tile
  bf16x8 qa[4];
  {
    const int tl = (rowQ & 63) + l16;             // w*16 + l16
    const short* qp = Qp + ((size_t)(rowQ >> 6) << 13) + tl*128;
    #pragma unroll
    for (int kk = 0; kk < 4; kk++)
      qa[kk] = *(const bf16x8*)(qp + (((kk*4 + quad) ^ (tl & 15)) << 3));
  }

  f32x4 o[8];
  #pragma unroll
  for (int e = 0; e < 8; e++) o[e] = (f32x4){0,0,0,0};
  float l[4] = {0,0,0,0};

  short* Pw = &Ps[w*1024];
  const int so = w*2048 + lane*8;
  const int nIter = qi + 1;

  for (int it = 0; it < nIter; ++it) {
    if (it) __syncthreads();                      // consumers done w/ prev tile
    {
      const short* kt = Kp + ((size_t)it << 13);
      const short* vt = Vp + ((size_t)it << 13);
      #pragma unroll
      for (int cc = 0; cc < 4; cc++) {
        gld16(kt + so + cc*512, &Ks[w*2048 + cc*512]);
        gld16(vt + so + cc*512, &Vs[w*2048 + cc*512]);
      }
    }
    __syncthreads();                              // vmcnt drained at barrier

    f32x4 s[4];
    #pragma unroll
    for (int nj = 0; nj < 4; nj++) s[nj] = (f32x4){0,0,0,0};
    #pragma unroll
    for (int kk = 0; kk < 4; kk++) {
      const int swz = ((kk*4 + quad) ^ l16) << 3;
      #pragma unroll
      for (int nj = 0; nj < 4; nj++) {
        bf16x8 kb = *(const bf16x8*)&Ks[(nj*16 + l16)*128 + swz];
        s[nj] = __builtin_amdgcn_mfma_f32_16x16x32_bf16(qa[kk], kb, s[nj], 0, 0, 0);
      }
    }

    if (it < qi) {                                // unmasked tile
      #pragma unroll
      for (int nj = 0; nj < 4; nj++) {
        #pragma unroll
        for (int r = 0; r < 4; r++) {
          float p = EXP2F(s[nj][r]);
          l[r] += p;
          const int row = quad*4 + r, col = nj*16 + l16;
          Pw[row*64 + (((col >> 3) ^ (row & 7)) << 3) + (col & 7)] = f2bf(p);
        }
      }
    } else {                                      // diagonal tile: mask
      const int s0 = it * 64;
      #pragma unroll
      for (int nj = 0; nj < 4; nj++) {
        const int key = s0 + nj*16 + l16;
        #pragma unroll
        for (int r = 0; r < 4; r++) {
          float p = (key > rowQ + quad*4 + r) ? 0.f : EXP2F(s[nj][r]);
          l[r] += p;
          const int row = quad*4 + r, col = nj*16 + l16;
          Pw[row*64 + (((col >> 3) ^ (row & 7)) << 3) + (col & 7)] = f2bf(p);
        }
      }
    }

    #pragma unroll
    for (int kk2 = 0; kk2 < 2; kk2++) {
      const int swz = ((kk2*4 + quad) ^ (l16 & 7)) << 3;
      bf16x8 pa = *(bf16x8*)&Pw[l16*64 + swz];
      #pragma unroll
      for (int e = 0; e < 8; e++) {
        bf16x8 vb = *(const bf16x8*)&Vs[(e*16 + l16)*64 + swz];
        o[e] = __builtin_amdgcn_mfma_f32_16x16x32_bf16(pa, vb, o[e], 0, 0, 0);
      }
    }
  }

  // epilogue: l-reduce, build 64x128 LDS image in Ks, b128 copy-out
  #pragma unroll
  for (int r = 0; r < 4; r++) {
    float t = l[r];
    t += __shfl_xor(t, 1); t += __shfl_xor(t, 2);
    t += __shfl_xor(t, 4); t += __shfl_xor(t, 8);
    l[r] = 1.0f / t;
  }
  __syncthreads();                                // done reading Ks/Vs
  #pragma unroll
  for (int e = 0; e < 8; e++) {
    const int c = e*2 + (l16 >> 3);
    #pragma unroll
    for (int r = 0; r < 4; r++) {
      const int lrow = w*16 + quad*4 + r;         // 0..63
      const int sub = lrow >> 5, r32 = lrow & 31;
      Ks[sub*4096 + r32*128 + ((c ^ (r32 & 15)) << 3) + (l16 & 7)] =
          f2bf(o[e][r] * l[r]);
    }
  }
  __syncthreads();
  const int st0 = b*64 + qi*2;
  #pragma unroll 2
  for (int i = tid; i < 1024; i += 256) {
    const int sub = i >> 9, rem = i & 511;
    short* dst = attnw + ((size_t)(st0 + sub)*8 + h)*4096 + rem*8;
    *(bf16x8*)dst = *(const bf16x8*)&Ks[i*8];
  }
}

// ---------------------------------------------------------------------------
// Kernel 3: Wu(1024x128 f32) -> WuT tile images (8 x 128n x 128k, swizzled).
// ---------------------------------------------------------------------------
__global__ __launch_bounds__(256) void wu_prep(
    const float* __restrict__ Wu, short* __restrict__ WuT)
{
  __shared__ __align__(16) short Tt[128*128];
  const int tid = threadIdx.x;
  const int kc = blockIdx.x;
  #pragma unroll 4
  for (int i = tid; i < 4096; i += 256) {
    int kl = i >> 5, n4 = (i & 31) << 2;
    float4 v = *(const float4*)&Wu[(size_t)(kc*128 + kl) * D_ + n4];
    float vv[4] = {v.x, v.y, v.z, v.w};
    #pragma unroll
    for (int j = 0; j < 4; j++) {
      int n = n4 + j;
      Tt[n*128 + (((kl >> 3) ^ (n & 15)) << 3) + (kl & 7)] = f2bf(vv[j]);
    }
  }
  __syncthreads();
  short* dst = WuT + (size_t)kc * 16384;
  #pragma unroll 2
  for (int i = tid; i < 2048; i += 256)
    *(bf16x8*)&dst[i*8] = *(bf16x8*)&Tt[i*8];
}

// ---------------------------------------------------------------------------
// Kernel 4: out_proj split-K=4, m-tile 128. grid (64 m, 4 kq) = 256 blocks
// (1/CU). B staged per block = 64KB (vs 2MB before: 1GB -> 32MB L2 traffic).
// Double-buffered over the 2 k-chunks. fp32 partials into pws (dead Qw).
// ---------------------------------------------------------------------------
__global__ __launch_bounds__(256) void out_proj(
    const short* __restrict__ attnw, const short* __restrict__ WuT,
    float* __restrict__ pws)
{
  __shared__ __align__(16) short As3[2][16384];
  __shared__ __align__(16) short Bs3[2][16384];
  const int tid = threadIdx.x;
  const int w = tid >> 6, lane = tid & 63, quad = lane >> 4, l16 = lane & 15;
  const int m0 = (int)blockIdx.x * 128;
  const int kq = (int)blockIdx.y;                 // 0..3, K-slice kq*256
  const int st0 = m0 >> 5;

  f32x4 acc[2][8];
  #pragma unroll
  for (int mi = 0; mi < 2; mi++)
    #pragma unroll
    for (int ni = 0; ni < 8; ni++) acc[mi][ni] = (f32x4){0,0,0,0};

  // stage chunk c (hc = kq*2+c) into buffer bufi; wave w stages sub-tile w
  {
    const int hc = kq*2;
    const short* ab = attnw + ((size_t)(st0 + w)*8 + hc)*4096;
    const short* bb = WuT + (size_t)hc*16384 + w*4096;
    #pragma unroll
    for (int cc = 0; cc < 8; cc++) {
      gld16(ab + cc*512 + lane*8, &As3[0][w*4096 + cc*512]);
      gld16(bb + cc*512 + lane*8, &Bs3[0][w*4096 + cc*512]);
    }
  }

  #pragma unroll
  for (int c = 0; c < 2; c++) {
    __syncthreads();                              // publish buf c
    if (c == 0) {                                 // prefetch chunk 1
      const int hc = kq*2 + 1;
      const short* ab = attnw + ((size_t)(st0 + w)*8 + hc)*4096;
      const short* bb = WuT + (size_t)hc*16384 + w*4096;
      #pragma unroll
      for (int cc = 0; cc < 8; cc++) {
        gld16(ab + cc*512 + lane*8, &As3[1][w*4096 + cc*512]);
        gld16(bb + cc*512 + lane*8, &Bs3[1][w*4096 + cc*512]);
      }
    }
    const short* as = &As3[c][0];
    const short* bs = &Bs3[c][0];
    #pragma unroll
    for (int kk = 0; kk < 4; kk++) {
      bf16x8 a[2], bf[8];
      #pragma unroll
      for (int mi = 0; mi < 2; mi++) {
        const int r32 = mi*16 + l16;
        a[mi] = *(const bf16x8*)&as[w*4096 + r32*128 +
                                    (((kk*4 + quad) ^ (r32 & 15)) << 3)];
      }
      #pragma unroll
      for (int ni = 0; ni < 8; ni++) {
        const int n = ni*16 + l16;
        bf[ni] = *(const bf16x8*)&bs[n*128 + (((kk*4 + quad) ^ (n & 15)) << 3)];
      }
      #pragma unroll
      for (int mi = 0; mi < 2; mi++)
        #pragma unroll
        for (int ni = 0; ni < 8; ni++)
          acc[mi][ni] = __builtin_amdgcn_mfma_f32_16x16x32_bf16(a[mi], bf[ni], acc[mi][ni], 0, 0, 0);
    }
  }

  float* dst = pws + (size_t)kq * (BT_ * D_);
  #pragma unroll
  for (int mi = 0; mi < 2; mi++) {
    #pragma unroll
    for (int ni = 0; ni < 8; ni++) {
      const int n = ni*16 + l16;
      #pragma unroll
      for (int r = 0; r < 4; r++) {
        const int m = m0 + w*32 + mi*16 + quad*4 + r;
        dst[(size_t)m*D_ + n] = acc[mi][ni][r];
      }
    }
  }
}

// ---------------------------------------------------------------------------
// Kernel 5: out = p0+p1+p2+p3 + bias. 1M f32 via float4. grid 512.
// ---------------------------------------------------------------------------
__global__ __launch_bounds__(256) void reduce_bias(
    const float* __restrict__ pws, const float* __restrict__ bu,
    float* __restrict__ out)
{
  const int base = ((int)blockIdx.x * 256 + (int)threadIdx.x) * 2;
  const float4* p0 = (const float4*)pws;
  const float4* p1 = p0 + (BT_ * D_ / 4);
  const float4* p2 = p1 + (BT_ * D_ / 4);
  const float4* p3 = p2 + (BT_ * D_ / 4);
  const float4* b4 = (const float4*)bu;
  float4* o4 = (float4*)out;
  #pragma unroll
  for (int j = 0; j < 2; j++) {
    int i = base + j;
    float4 a = p0[i], b = p1[i], c = p2[i], d = p3[i], e = b4[i & 31];
    float4 r;
    r.x = a.x + b.x + c.x + d.x + e.x;
    r.y = a.y + b.y + c.y + d.y + e.y;
    r.z = a.z + b.z + c.z + d.z + e.z;
    r.w = a.w + b.w + c.w + d.w + e.w;
    o4[i] = r;
  }
}

extern "C" void kernel_launch(void* const* d_in, const int* in_sizes, int n_in,
                              void* d_out, int out_size, void* d_ws, size_t ws_size,
                              hipStream_t stream) {
  (void)in_sizes; (void)n_in; (void)out_size; (void)ws_size;
  const float* x  = (const float*)d_in[0];
  const float* Wq = (const float*)d_in[1];
  const float* Wk = (const float*)d_in[2];
  const float* Wv = (const float*)d_in[3];
  const float* Wu = (const float*)d_in[4];
  const float* bu = (const float*)d_in[5];
  float* out = (float*)d_out;

  const size_t headElems = (size_t)B_ * H_ * T_ * D_;   // 8,388,608
  short* Qw    = (short*)d_ws;
  short* Kw    = Qw + headElems;
  short* Vw    = Kw + headElems;
  short* attnw = Vw + headElems;                        // 16 MB (tiled images)
  short* xbf = attnw;                                   // prep outputs live in
  short* WT  = attnw + 1048576;                         // not-yet-written attnw
  short* WuT = Kw;                                      // Kw dead after attn
  float* pws = (float*)Qw;                              // Qw dead after attn (16MB)

  prep<<<dim3(88), 256, 0, stream>>>(x, Wq, Wk, Wv, xbf, WT);
  qkv_proj<<<dim3(64, 24), 256, 0, stream>>>(xbf, WT, Qw, Kw, Vw);
  attn_kernel<<<dim3(1024), 256, 0, stream>>>(Qw, Kw, Vw, attnw);
  wu_prep<<<dim3(8), 256, 0, stream>>>(Wu, WuT);
  out_proj<<<dim3(64, 4), 256, 0, stream>>>(attnw, WuT, pws);
  reduce_bias<<<dim3(512), 256, 0, stream>>>(pws, bu, out);
}

// Round 11
// 159.235 us; speedup vs baseline: 1.2076x; 1.0453x over previous
//
#include <hip/hip_runtime.h>
#include <hip/hip_bf16.h>
#include <math.h>

#define B_ 4
#define T_ 2048
#define D_ 128
#define H_ 8
#define BT_ 8192
#define HD_ 1024

typedef __attribute__((ext_vector_type(8))) short bf16x8;
typedef __attribute__((ext_vector_type(4))) float f32x4;

__device__ __forceinline__ short f2bf(float f) {
  union { float f; unsigned u; } v; v.f = f;
  return (short)((v.u + 0x8000u) >> 16);
}

#if __has_builtin(__builtin_amdgcn_exp2f)
#define EXP2F(x) __builtin_amdgcn_exp2f(x)
#else
#define EXP2F(x) exp2f(x)
#endif

#define QSCALE 0.12752040242046492f   // k^-0.5 * log2(e), folded into Q
#define VSCALE 0.29730177875068026f   // k^-0.25, folded into V

// async global->LDS DMA, 16B/lane; LDS dest = wave-uniform base + lane*16
__device__ __forceinline__ void gld16(const short* g, short* l) {
  __builtin_amdgcn_global_load_lds(
      (const __attribute__((address_space(1))) void*)g,
      (__attribute__((address_space(3))) void*)l, 16, 0, 0);
}

// ---------------------------------------------------------------------------
// Kernel 0: prep. blocks 0..23: Wq/Wk/Wv -> WT swizzled tile images.
// blocks 24..87: x -> xbf swizzled tile images.
// ---------------------------------------------------------------------------
__global__ __launch_bounds__(256) void prep(
    const float* __restrict__ x, const float* __restrict__ Wq,
    const float* __restrict__ Wk, const float* __restrict__ Wv,
    short* __restrict__ xbf, short* __restrict__ WT)
{
  __shared__ __align__(16) short Tt[128*128];
  const int tid = threadIdx.x;
  const int id = blockIdx.x;
  if (id < 24) {
    const int wsel = id >> 3, nt = id & 7;
    const float* W = (wsel == 0) ? Wq : (wsel == 1) ? Wk : Wv;
    #pragma unroll 4
    for (int i = tid; i < 4096; i += 256) {
      int k = i >> 5, n4 = (i & 31) << 2;
      float4 v = *(const float4*)&W[(size_t)k * HD_ + nt*128 + n4];
      float vv[4] = {v.x, v.y, v.z, v.w};
      #pragma unroll
      for (int j = 0; j < 4; j++) {
        int n = n4 + j;
        Tt[n*128 + (((k >> 3) ^ (n & 15)) << 3) + (k & 7)] = f2bf(vv[j]);
      }
    }
    __syncthreads();
    short* dst = WT + (size_t)id * 16384;
    #pragma unroll 2
    for (int i = tid; i < 2048; i += 256)
      *(bf16x8*)&dst[i*8] = *(bf16x8*)&Tt[i*8];
  } else {
    const int xb = id - 24;                       // 64 tiles
    const float* xs = x + (size_t)xb * 16384;
    short* dst = xbf + (size_t)xb * 16384;
    #pragma unroll 4
    for (int i = tid; i < 4096; i += 256) {
      float4 v = ((const float4*)xs)[i];
      int row = i >> 5, c = (i & 31) >> 1, half = i & 1;
      short4 p;
      p.x = f2bf(v.x); p.y = f2bf(v.y); p.z = f2bf(v.z); p.w = f2bf(v.w);
      *(short4*)&dst[(row*16 + (c ^ (row & 15)))*8 + half*4] = p;
    }
  }
}

// ---------------------------------------------------------------------------
// Kernel 1: QKV GEMM, fully DMA-staged. grid (64 m, 24 n=wsel*8+head).
// For Q/K the MFMA operands are SWAPPED (A=W rows -> C=[d][t]) so the 4
// accumulator regs span 4 consecutive d -> short4 image stores (16/thread,
// was 64 scalar). V keeps A=x orientation (regs span consecutive t, short4).
// Epilogue: LDS tile image + linear 32KB b128 copy-out.
// ---------------------------------------------------------------------------
__global__ __launch_bounds__(256, 2) void qkv_proj(
    const short* __restrict__ xbf, const short* __restrict__ WT,
    short* __restrict__ Qw, short* __restrict__ Kw, short* __restrict__ Vw)
{
  __shared__ __align__(16) short As[16384];
  __shared__ __align__(16) short Bs[16384];
  const int tid = threadIdx.x;
  const int w = tid >> 6, lane = tid & 63, quad = lane >> 4, l16 = lane & 15;
  const int m0 = blockIdx.x * 128;

  {
    const short* asrc = xbf + (size_t)blockIdx.x * 16384;
    const short* bsrc = WT + (size_t)blockIdx.y * 16384;
    const int so = w*4096 + lane*8;
    #pragma unroll
    for (int cc = 0; cc < 8; cc++) {
      gld16(asrc + so + cc*512, &As[w*4096 + cc*512]);
      gld16(bsrc + so + cc*512, &Bs[w*4096 + cc*512]);
    }
  }
  __syncthreads();

  const int wsel = (int)blockIdx.y >> 3;
  const int rA0 = (w & 1) * 64, rB0 = (w >> 1) * 64;
  // Q/K: A-operand = W rows (d), B = x rows (t). V: A = x rows, B = W rows.
  const short* RA = (wsel <= 1) ? Bs : As;
  const short* RB = (wsel <= 1) ? As : Bs;

  f32x4 acc[4][4];
  #pragma unroll
  for (int a = 0; a < 4; a++)
    #pragma unroll
    for (int b = 0; b < 4; b++) acc[a][b] = (f32x4){0.f, 0.f, 0.f, 0.f};

  #pragma unroll
  for (int kk = 0; kk < 4; kk++) {
    const int swz = ((kk*4 + quad) ^ l16) << 3;
    bf16x8 af[4], bfv[4];
    #pragma unroll
    for (int ai = 0; ai < 4; ai++) af[ai]  = *(const bf16x8*)&RA[(rA0 + ai*16 + l16)*128 + swz];
    #pragma unroll
    for (int bi = 0; bi < 4; bi++) bfv[bi] = *(const bf16x8*)&RB[(rB0 + bi*16 + l16)*128 + swz];
    #pragma unroll
    for (int ai = 0; ai < 4; ai++)
      #pragma unroll
      for (int bi = 0; bi < 4; bi++)
        acc[ai][bi] = __builtin_amdgcn_mfma_f32_16x16x32_bf16(af[ai], bfv[bi], acc[ai][bi], 0, 0, 0);
  }

  __syncthreads();     // all MFMA reads of As/Bs done; reuse As as image
  if (wsel <= 1) {
    const float sc = wsel ? 1.0f : QSCALE;
    #pragma unroll
    for (int ai = 0; ai < 4; ai++) {
      #pragma unroll
      for (int bi = 0; bi < 4; bi++) {
        const int d0 = rA0 + ai*16 + quad*4;      // 4 consecutive d
        const int t  = rB0 + bi*16 + l16;
        const int tile = t >> 6, tl = t & 63;
        short4 p;
        p.x = f2bf(acc[ai][bi][0] * sc);
        p.y = f2bf(acc[ai][bi][1] * sc);
        p.z = f2bf(acc[ai][bi][2] * sc);
        p.w = f2bf(acc[ai][bi][3] * sc);
        *(short4*)&As[tile*8192 + tl*128 + (((d0 >> 3) ^ (tl & 15)) << 3) + (d0 & 7)] = p;
      }
    }
  } else {
    #pragma unroll
    for (int ai = 0; ai < 4; ai++) {
      #pragma unroll
      for (int bi = 0; bi < 4; bi++) {
        const int t0 = rA0 + ai*16 + quad*4;      // 4 consecutive t
        const int d  = rB0 + bi*16 + l16;
        const int tile = t0 >> 6, tl0 = t0 & 63;
        short4 p;
        p.x = f2bf(acc[ai][bi][0] * VSCALE);
        p.y = f2bf(acc[ai][bi][1] * VSCALE);
        p.z = f2bf(acc[ai][bi][2] * VSCALE);
        p.w = f2bf(acc[ai][bi][3] * VSCALE);
        *(short4*)&As[tile*8192 + d*64 + (((tl0 >> 3) ^ (d & 7)) << 3) + (tl0 & 7)] = p;
      }
    }
  }
  __syncthreads();

  const int h = (int)blockIdx.y & 7;
  const int b = m0 >> 11, t0 = m0 & 2047;
  short* base = ((wsel == 0) ? Qw : (wsel == 1) ? Kw : Vw)
              + (size_t)(b*H_ + h)*262144 + (size_t)t0*128;
  #pragma unroll 2
  for (int i = tid; i < 2048; i += 256)
    *(bf16x8*)&base[i*8] = *(bf16x8*)&As[i*8];
}

// ---------------------------------------------------------------------------
// Kernel 2: causal flash attention — r5 structure (measured plateau 63.5-64).
// One 64-row q-tile per block, grid 1024 (4 blocks/CU, 16 waves/CU, 40KB
// LDS). Single-buffer DMA staging, two barriers/iter, TLP-covered latency.
// qi from slot=(j&3)^((j>>5)&3): co-resident groups of 4 sum to 66 iters.
// ---------------------------------------------------------------------------
__global__ __launch_bounds__(256, 4) void attn_kernel(
    const short* __restrict__ Qw, const short* __restrict__ Kw,
    const short* __restrict__ Vw, short* __restrict__ attnw)
{
  __shared__ __align__(16) short Ks[8192];        // 64t x 128d swizzled
  __shared__ __align__(16) short Vs[8192];        // 128d x 64t swizzled
  __shared__ __align__(16) short Ps[4096];        // 4 waves x 16x64

  const int tid = threadIdx.x;
  const int id = (int)blockIdx.x;                 // 1024 blocks
  const int xcd = id & 7;
  const int j   = id >> 3;                        // 0..127 within XCD
  const int u   = j & 3;
  const int q   = (j >> 2) & 7;
  const int vv  = (j >> 5) & 3;
  const int slot = u ^ vv;
  const int qi = (slot == 0) ? q : (slot == 1) ? 15 - q
               : (slot == 2) ? 16 + q : 31 - q;
  const int bh = xcd | (u << 3);
  const int b = bh >> 3, h = bh & 7;
  const int w = tid >> 6, lane = tid & 63, quad = lane >> 4, l16 = lane & 15;
  const int rowQ = qi*64 + w*16;

  const short* Qp = Qw + (size_t)bh * 262144;     // swizzled 16KB tiles
  const short* Kp = Kw + (size_t)bh * 262144;
  const short* Vp = Vw + (size_t)bh * 262144;

  bf16x8 qa[4];
  {
    const int tl = (rowQ & 63) + l16;
    const short* qp = Qp + ((size_t)(rowQ >> 6) << 13) + tl*128;
    #pragma unroll
    for (int kk = 0; kk < 4; kk++)
      qa[kk] = *(const bf16x8*)(qp + (((kk*4 + quad) ^ (tl & 15)) << 3));
  }

  f32x4 o[8];
  #pragma unroll
  for (int e = 0; e < 8; e++) o[e] = (f32x4){0,0,0,0};
  float l[4] = {0,0,0,0};

  short* Pw = &Ps[w*1024];
  const int so = w*2048 + lane*8;
  const int nIter = qi + 1;

  for (int it = 0; it < nIter; ++it) {
    if (it) __syncthreads();                      // consumers done w/ prev tile
    {
      const short* kt = Kp + ((size_t)it << 13);
      const short* vt = Vp + ((size_t)it << 13);
      #pragma unroll
      for (int cc = 0; cc < 4; cc++) {
        gld16(kt + so + cc*512, &Ks[w*2048 + cc*512]);
        gld16(vt + so + cc*512, &Vs[w*2048 + cc*512]);
      }
    }
    __syncthreads();                              // vmcnt drained at barrier

    f32x4 s[4];
    #pragma unroll
    for (int nj = 0; nj < 4; nj++) s[nj] = (f32x4){0,0,0,0};
    #pragma unroll
    for (int kk = 0; kk < 4; kk++) {
      const int swz = ((kk*4 + quad) ^ l16) << 3;
      #pragma unroll
      for (int nj = 0; nj < 4; nj++) {
        bf16x8 kb = *(const bf16x8*)&Ks[(nj*16 + l16)*128 + swz];
        s[nj] = __builtin_amdgcn_mfma_f32_16x16x32_bf16(qa[kk], kb, s[nj], 0, 0, 0);
      }
    }

    if (it < qi) {                                // unmasked tile
      #pragma unroll
      for (int nj = 0; nj < 4; nj++) {
        #pragma unroll
        for (int r = 0; r < 4; r++) {
          float p = EXP2F(s[nj][r]);
          l[r] += p;
          const int row = quad*4 + r, col = nj*16 + l16;
          Pw[row*64 + (((col >> 3) ^ (row & 7)) << 3) + (col & 7)] = f2bf(p);
        }
      }
    } else {                                      // diagonal tile: mask
      const int s0 = it * 64;
      #pragma unroll
      for (int nj = 0; nj < 4; nj++) {
        const int key = s0 + nj*16 + l16;
        #pragma unroll
        for (int r = 0; r < 4; r++) {
          float p = (key > rowQ + quad*4 + r) ? 0.f : EXP2F(s[nj][r]);
          l[r] += p;
          const int row = quad*4 + r, col = nj*16 + l16;
          Pw[row*64 + (((col >> 3) ^ (row & 7)) << 3) + (col & 7)] = f2bf(p);
        }
      }
    }

    #pragma unroll
    for (int kk2 = 0; kk2 < 2; kk2++) {
      const int swz = ((kk2*4 + quad) ^ (l16 & 7)) << 3;
      bf16x8 pa = *(bf16x8*)&Pw[l16*64 + swz];
      #pragma unroll
      for (int e = 0; e < 8; e++) {
        bf16x8 vb = *(const bf16x8*)&Vs[(e*16 + l16)*64 + swz];
        o[e] = __builtin_amdgcn_mfma_f32_16x16x32_bf16(pa, vb, o[e], 0, 0, 0);
      }
    }
  }

  // epilogue: l-reduce, build 64x128 LDS image in Ks, b128 copy-out
  #pragma unroll
  for (int r = 0; r < 4; r++) {
    float t = l[r];
    t += __shfl_xor(t, 1); t += __shfl_xor(t, 2);
    t += __shfl_xor(t, 4); t += __shfl_xor(t, 8);
    l[r] = 1.0f / t;
  }
  __syncthreads();                                // done reading Ks/Vs
  #pragma unroll
  for (int e = 0; e < 8; e++) {
    const int c = e*2 + (l16 >> 3);
    #pragma unroll
    for (int r = 0; r < 4; r++) {
      const int lrow = w*16 + quad*4 + r;         // 0..63
      const int sub = lrow >> 5, r32 = lrow & 31;
      Ks[sub*4096 + r32*128 + ((c ^ (r32 & 15)) << 3) + (l16 & 7)] =
          f2bf(o[e][r] * l[r]);
    }
  }
  __syncthreads();
  const int st0 = b*64 + qi*2;
  #pragma unroll 2
  for (int i = tid; i < 1024; i += 256) {
    const int sub = i >> 9, rem = i & 511;
    short* dst = attnw + ((size_t)(st0 + sub)*8 + h)*4096 + rem*8;
    *(bf16x8*)dst = *(const bf16x8*)&Ks[i*8];
  }
}

// ---------------------------------------------------------------------------
// Kernel 3: Wu(1024x128 f32) -> WuT tile images (8 x 128n x 128k, swizzled).
// ---------------------------------------------------------------------------
__global__ __launch_bounds__(256) void wu_prep(
    const float* __restrict__ Wu, short* __restrict__ WuT)
{
  __shared__ __align__(16) short Tt[128*128];
  const int tid = threadIdx.x;
  const int kc = blockIdx.x;
  #pragma unroll 4
  for (int i = tid; i < 4096; i += 256) {
    int kl = i >> 5, n4 = (i & 31) << 2;
    float4 v = *(const float4*)&Wu[(size_t)(kc*128 + kl) * D_ + n4];
    float vv[4] = {v.x, v.y, v.z, v.w};
    #pragma unroll
    for (int j = 0; j < 4; j++) {
      int n = n4 + j;
      Tt[n*128 + (((kl >> 3) ^ (n & 15)) << 3) + (kl & 7)] = f2bf(vv[j]);
    }
  }
  __syncthreads();
  short* dst = WuT + (size_t)kc * 16384;
  #pragma unroll 2
  for (int i = tid; i < 2048; i += 256)
    *(bf16x8*)&dst[i*8] = *(bf16x8*)&Tt[i*8];
}

// ---------------------------------------------------------------------------
// Kernel 4: out = attn @ Wu + bu -> fp32. DMA-staged, double-buffered over
// 8 k-chunks, fused bias. grid 512 (m-tile 16), 2 blocks/CU. (r6 structure)
// ---------------------------------------------------------------------------
__global__ __launch_bounds__(256, 2) void out_proj(
    const short* __restrict__ attnw, const short* __restrict__ WuT,
    const float* __restrict__ bu, float* __restrict__ out)
{
  __shared__ __align__(16) short As2[2][2048];
  __shared__ __align__(16) short Bs2[2][16384];
  const int tid = threadIdx.x;
  const int w = tid >> 6, lane = tid & 63, quad = lane >> 4, l16 = lane & 15;
  const int m0 = (int)blockIdx.x * 16;
  const int mtile32 = m0 >> 5, half = (m0 >> 4) & 1;

  f32x4 o2[2];
  o2[0] = (f32x4){0,0,0,0}; o2[1] = (f32x4){0,0,0,0};

  {
    const short* ab = attnw + (size_t)(mtile32*8)*4096 + half*2048;
    gld16(ab + w*512 + lane*8, &As2[0][w*512]);
    #pragma unroll
    for (int cc = 0; cc < 8; cc++)
      gld16(WuT + w*4096 + cc*512 + lane*8, &Bs2[0][w*4096 + cc*512]);
  }
  int buf = 0;

  for (int kc = 0; kc < 8; kc++) {
    __syncthreads();
    if (kc < 7) {
      const short* ab = attnw + (size_t)(mtile32*8 + kc + 1)*4096 + half*2048;
      const short* bb = WuT + (size_t)(kc + 1)*16384;
      gld16(ab + w*512 + lane*8, &As2[buf^1][w*512]);
      #pragma unroll
      for (int cc = 0; cc < 8; cc++)
        gld16(bb + w*4096 + cc*512 + lane*8, &Bs2[buf^1][w*4096 + cc*512]);
    }
    const short* as = &As2[buf][0];
    const short* bs = &Bs2[buf][0];
    #pragma unroll
    for (int kk = 0; kk < 4; kk++) {
      const int swz = ((kk*4 + quad) ^ l16) << 3;
      bf16x8 a = *(const bf16x8*)&as[l16*128 + swz];
      #pragma unroll
      for (int e = 0; e < 2; e++) {
        bf16x8 bfr = *(const bf16x8*)&bs[((w*2 + e)*16 + l16)*128 + swz];
        o2[e] = __builtin_amdgcn_mfma_f32_16x16x32_bf16(a, bfr, o2[e], 0, 0, 0);
      }
    }
    buf ^= 1;
  }

  #pragma unroll
  for (int e = 0; e < 2; e++) {
    const int n = (w*2 + e)*16 + l16;
    const float bias = bu[n];
    #pragma unroll
    for (int r = 0; r < 4; r++) {
      const int mm = m0 + quad*4 + r;
      out[(size_t)mm*D_ + n] = o2[e][r] + bias;
    }
  }
}

extern "C" void kernel_launch(void* const* d_in, const int* in_sizes, int n_in,
                              void* d_out, int out_size, void* d_ws, size_t ws_size,
                              hipStream_t stream) {
  (void)in_sizes; (void)n_in; (void)out_size; (void)ws_size;
  const float* x  = (const float*)d_in[0];
  const float* Wq = (const float*)d_in[1];
  const float* Wk = (const float*)d_in[2];
  const float* Wv = (const float*)d_in[3];
  const float* Wu = (const float*)d_in[4];
  const float* bu = (const float*)d_in[5];
  float* out = (float*)d_out;

  const size_t headElems = (size_t)B_ * H_ * T_ * D_;   // 8,388,608
  short* Qw    = (short*)d_ws;
  short* Kw    = Qw + headElems;
  short* Vw    = Kw + headElems;
  short* attnw = Vw + headElems;                        // 16 MB (tiled images)
  short* xbf = attnw;                                   // prep outputs live in
  short* WT  = attnw + 1048576;                         // not-yet-written attnw
  short* WuT = Kw;                                      // Kw dead after attn

  prep<<<dim3(88), 256, 0, stream>>>(x, Wq, Wk, Wv, xbf, WT);
  qkv_proj<<<dim3(64, 24), 256, 0, stream>>>(xbf, WT, Qw, Kw, Vw);
  attn_kernel<<<dim3(1024), 256, 0, stream>>>(Qw, Kw, Vw, attnw);
  wu_prep<<<dim3(8), 256, 0, stream>>>(Wu, WuT);
  out_proj<<<dim3(512), 256, 0, stream>>>(attnw, WuT, bu, out);
}

// Round 12
// 152.754 us; speedup vs baseline: 1.2588x; 1.0424x over previous
//
#include <hip/hip_runtime.h>
#include <hip/hip_bf16.h>
#include <math.h>

#define B_ 4
#define T_ 2048
#define D_ 128
#define H_ 8
#define BT_ 8192
#define HD_ 1024

typedef __attribute__((ext_vector_type(8))) short bf16x8;
typedef __attribute__((ext_vector_type(4))) float f32x4;

__device__ __forceinline__ short f2bf(float f) {
  union { float f; unsigned u; } v; v.f = f;
  return (short)((v.u + 0x8000u) >> 16);
}

#if __has_builtin(__builtin_amdgcn_exp2f)
#define EXP2F(x) __builtin_amdgcn_exp2f(x)
#else
#define EXP2F(x) exp2f(x)
#endif

#define QSCALE 0.12752040242046492f   // k^-0.5 * log2(e), folded into Q
#define VSCALE 0.29730177875068026f   // k^-0.25, folded into V

// async global->LDS DMA, 16B/lane; LDS dest = wave-uniform base + lane*16
__device__ __forceinline__ void gld16(const short* g, short* l) {
  __builtin_amdgcn_global_load_lds(
      (const __attribute__((address_space(1))) void*)g,
      (__attribute__((address_space(3))) void*)l, 16, 0, 0);
}

__device__ __forceinline__ void wu_transpose_body(
    const float* __restrict__ Wu, short* __restrict__ WuT,
    short* Tt, int kc, int tid)
{
  #pragma unroll 4
  for (int i = tid; i < 4096; i += 256) {
    int kl = i >> 5, n4 = (i & 31) << 2;
    float4 v = *(const float4*)&Wu[(size_t)(kc*128 + kl) * D_ + n4];
    float vv[4] = {v.x, v.y, v.z, v.w};
    #pragma unroll
    for (int j = 0; j < 4; j++) {
      int n = n4 + j;
      Tt[n*128 + (((kl >> 3) ^ (n & 15)) << 3) + (kl & 7)] = f2bf(vv[j]);
    }
  }
  __syncthreads();
  short* dst = WuT + (size_t)kc * 16384;
  #pragma unroll 2
  for (int i = tid; i < 2048; i += 256)
    *(bf16x8*)&dst[i*8] = *(bf16x8*)&Tt[i*8];
}

// ---------------------------------------------------------------------------
// Kernel 0: prep. blocks 0..23: Wq/Wk/Wv -> WT swizzled tile images.
// blocks 24..87: x -> xbf swizzled tile images. blocks 88..95 (only when
// launched with 96 blocks, i.e. ws has room for a standalone WuT): Wu
// transpose -> WuT tile images.
// ---------------------------------------------------------------------------
__global__ __launch_bounds__(256) void prep(
    const float* __restrict__ x, const float* __restrict__ Wq,
    const float* __restrict__ Wk, const float* __restrict__ Wv,
    const float* __restrict__ Wu,
    short* __restrict__ xbf, short* __restrict__ WT, short* __restrict__ WuT)
{
  __shared__ __align__(16) short Tt[128*128];
  const int tid = threadIdx.x;
  const int id = blockIdx.x;
  if (id < 24) {
    const int wsel = id >> 3, nt = id & 7;
    const float* W = (wsel == 0) ? Wq : (wsel == 1) ? Wk : Wv;
    #pragma unroll 4
    for (int i = tid; i < 4096; i += 256) {
      int k = i >> 5, n4 = (i & 31) << 2;
      float4 v = *(const float4*)&W[(size_t)k * HD_ + nt*128 + n4];
      float vv[4] = {v.x, v.y, v.z, v.w};
      #pragma unroll
      for (int j = 0; j < 4; j++) {
        int n = n4 + j;
        Tt[n*128 + (((k >> 3) ^ (n & 15)) << 3) + (k & 7)] = f2bf(vv[j]);
      }
    }
    __syncthreads();
    short* dst = WT + (size_t)id * 16384;
    #pragma unroll 2
    for (int i = tid; i < 2048; i += 256)
      *(bf16x8*)&dst[i*8] = *(bf16x8*)&Tt[i*8];
  } else if (id < 88) {
    const int xb = id - 24;                       // 64 tiles
    const float* xs = x + (size_t)xb * 16384;
    short* dst = xbf + (size_t)xb * 16384;
    #pragma unroll 4
    for (int i = tid; i < 4096; i += 256) {
      float4 v = ((const float4*)xs)[i];
      int row = i >> 5, c = (i & 31) >> 1, half = i & 1;
      short4 p;
      p.x = f2bf(v.x); p.y = f2bf(v.y); p.z = f2bf(v.z); p.w = f2bf(v.w);
      *(short4*)&dst[(row*16 + (c ^ (row & 15)))*8 + half*4] = p;
    }
  } else {
    wu_transpose_body(Wu, WuT, Tt, id - 88, tid);
  }
}

// ---------------------------------------------------------------------------
// Kernel 1: QKV GEMM. grid (64 m, 8 head) = 512 blocks, 2/CU, ONE block-wave.
// x tile staged ONCE per block (A-reuse x3); per-wsel B DMA into Bs, which
// doubles as the epilogue image after MFMA reads complete. Q/K use swapped
// operands (A=W rows) so acc regs span 4 consecutive d -> short4 stores.
// ---------------------------------------------------------------------------
__global__ __launch_bounds__(256, 2) void qkv_proj(
    const short* __restrict__ xbf, const short* __restrict__ WT,
    short* __restrict__ Qw, short* __restrict__ Kw, short* __restrict__ Vw)
{
  __shared__ __align__(16) short As[16384];
  __shared__ __align__(16) short Bs[16384];
  const int tid = threadIdx.x;
  const int w = tid >> 6, lane = tid & 63, quad = lane >> 4, l16 = lane & 15;
  const int m0 = (int)blockIdx.x * 128;
  const int head = (int)blockIdx.y;
  const int so = w*4096 + lane*8;

  {                                               // prologue: A + B(wsel 0)
    const short* asrc = xbf + (size_t)blockIdx.x * 16384;
    const short* bsrc = WT + (size_t)head * 16384;
    #pragma unroll
    for (int cc = 0; cc < 8; cc++) {
      gld16(asrc + so + cc*512, &As[w*4096 + cc*512]);
      gld16(bsrc + so + cc*512, &Bs[w*4096 + cc*512]);
    }
  }

  const int rA0 = (w & 1) * 64, rB0 = (w >> 1) * 64;
  const int b = m0 >> 11, t0g = m0 & 2047;
  const int h = head;

  #pragma unroll 1
  for (int wsel = 0; wsel < 3; wsel++) {
    __syncthreads();                              // B DMA drained at barrier
    // Q/K: A-operand = W rows (d). V: A = x rows (t).
    const short* RA = (wsel <= 1) ? Bs : As;
    const short* RB = (wsel <= 1) ? As : Bs;

    f32x4 acc[4][4];
    #pragma unroll
    for (int a = 0; a < 4; a++)
      #pragma unroll
      for (int bb = 0; bb < 4; bb++) acc[a][bb] = (f32x4){0.f, 0.f, 0.f, 0.f};

    #pragma unroll
    for (int kk = 0; kk < 4; kk++) {
      const int swz = ((kk*4 + quad) ^ l16) << 3;
      bf16x8 af[4], bfv[4];
      #pragma unroll
      for (int ai = 0; ai < 4; ai++) af[ai]  = *(const bf16x8*)&RA[(rA0 + ai*16 + l16)*128 + swz];
      #pragma unroll
      for (int bi = 0; bi < 4; bi++) bfv[bi] = *(const bf16x8*)&RB[(rB0 + bi*16 + l16)*128 + swz];
      #pragma unroll
      for (int ai = 0; ai < 4; ai++)
        #pragma unroll
        for (int bi = 0; bi < 4; bi++)
          acc[ai][bi] = __builtin_amdgcn_mfma_f32_16x16x32_bf16(af[ai], bfv[bi], acc[ai][bi], 0, 0, 0);
    }

    __syncthreads();   // MFMA reads of Bs complete; Bs becomes the image
    if (wsel <= 1) {
      const float sc = wsel ? 1.0f : QSCALE;
      #pragma unroll
      for (int ai = 0; ai < 4; ai++) {
        #pragma unroll
        for (int bi = 0; bi < 4; bi++) {
          const int d0 = rA0 + ai*16 + quad*4;    // 4 consecutive d
          const int t  = rB0 + bi*16 + l16;
          const int tile = t >> 6, tl = t & 63;
          short4 p;
          p.x = f2bf(acc[ai][bi][0] * sc);
          p.y = f2bf(acc[ai][bi][1] * sc);
          p.z = f2bf(acc[ai][bi][2] * sc);
          p.w = f2bf(acc[ai][bi][3] * sc);
          *(short4*)&Bs[tile*8192 + tl*128 + (((d0 >> 3) ^ (tl & 15)) << 3) + (d0 & 7)] = p;
        }
      }
    } else {
      #pragma unroll
      for (int ai = 0; ai < 4; ai++) {
        #pragma unroll
        for (int bi = 0; bi < 4; bi++) {
          const int t0 = rA0 + ai*16 + quad*4;    // 4 consecutive t
          const int d  = rB0 + bi*16 + l16;
          const int tile = t0 >> 6, tl0 = t0 & 63;
          short4 p;
          p.x = f2bf(acc[ai][bi][0] * VSCALE);
          p.y = f2bf(acc[ai][bi][1] * VSCALE);
          p.z = f2bf(acc[ai][bi][2] * VSCALE);
          p.w = f2bf(acc[ai][bi][3] * VSCALE);
          *(short4*)&Bs[tile*8192 + d*64 + (((tl0 >> 3) ^ (d & 7)) << 3) + (tl0 & 7)] = p;
        }
      }
    }
    __syncthreads();                              // image complete

    short* base = ((wsel == 0) ? Qw : (wsel == 1) ? Kw : Vw)
                + (size_t)(b*H_ + h)*262144 + (size_t)t0g*128;
    #pragma unroll 2
    for (int i = tid; i < 2048; i += 256)
      *(bf16x8*)&base[i*8] = *(bf16x8*)&Bs[i*8];

    if (wsel < 2) {
      __syncthreads();                            // copy-out reads done
      const short* bsrc = WT + (size_t)((wsel + 1)*8 + head) * 16384;
      #pragma unroll
      for (int cc = 0; cc < 8; cc++)
        gld16(bsrc + so + cc*512, &Bs[w*4096 + cc*512]);
    }
  }
}

// ---------------------------------------------------------------------------
// Kernel 2: causal flash attention — r5 structure (measured plateau ~64 us).
// One 64-row q-tile per block, grid 1024 (4 blocks/CU, 16 waves/CU, 40KB
// LDS). Single-buffer DMA staging, two barriers/iter, TLP-covered latency.
// qi from slot=(j&3)^((j>>5)&3): co-resident groups of 4 sum to 66 iters.
// ---------------------------------------------------------------------------
__global__ __launch_bounds__(256, 4) void attn_kernel(
    const short* __restrict__ Qw, const short* __restrict__ Kw,
    const short* __restrict__ Vw, short* __restrict__ attnw)
{
  __shared__ __align__(16) short Ks[8192];        // 64t x 128d swizzled
  __shared__ __align__(16) short Vs[8192];        // 128d x 64t swizzled
  __shared__ __align__(16) short Ps[4096];        // 4 waves x 16x64

  const int tid = threadIdx.x;
  const int id = (int)blockIdx.x;                 // 1024 blocks
  const int xcd = id & 7;
  const int j   = id >> 3;                        // 0..127 within XCD
  const int u   = j & 3;
  const int q   = (j >> 2) & 7;
  const int vv  = (j >> 5) & 3;
  const int slot = u ^ vv;
  const int qi = (slot == 0) ? q : (slot == 1) ? 15 - q
               : (slot == 2) ? 16 + q : 31 - q;
  const int bh = xcd | (u << 3);
  const int b = bh >> 3, h = bh & 7;
  const int w = tid >> 6, lane = tid & 63, quad = lane >> 4, l16 = lane & 15;
  const int rowQ = qi*64 + w*16;

  const short* Qp = Qw + (size_t)bh * 262144;     // swizzled 16KB tiles
  const short* Kp = Kw + (size_t)bh * 262144;
  const short* Vp = Vw + (size_t)bh * 262144;

  bf16x8 qa[4];
  {
    const int tl = (rowQ & 63) + l16;
    const short* qp = Qp + ((size_t)(rowQ >> 6) << 13) + tl*128;
    #pragma unroll
    for (int kk = 0; kk < 4; kk++)
      qa[kk] = *(const bf16x8*)(qp + (((kk*4 + quad) ^ (tl & 15)) << 3));
  }

  f32x4 o[8];
  #pragma unroll
  for (int e = 0; e < 8; e++) o[e] = (f32x4){0,0,0,0};
  float l[4] = {0,0,0,0};

  short* Pw = &Ps[w*1024];
  const int so = w*2048 + lane*8;
  const int nIter = qi + 1;

  for (int it = 0; it < nIter; ++it) {
    if (it) __syncthreads();                      // consumers done w/ prev tile
    {
      const short* kt = Kp + ((size_t)it << 13);
      const short* vt = Vp + ((size_t)it << 13);
      #pragma unroll
      for (int cc = 0; cc < 4; cc++) {
        gld16(kt + so + cc*512, &Ks[w*2048 + cc*512]);
        gld16(vt + so + cc*512, &Vs[w*2048 + cc*512]);
      }
    }
    __syncthreads();                              // vmcnt drained at barrier

    f32x4 s[4];
    #pragma unroll
    for (int nj = 0; nj < 4; nj++) s[nj] = (f32x4){0,0,0,0};
    #pragma unroll
    for (int kk = 0; kk < 4; kk++) {
      const int swz = ((kk*4 + quad) ^ l16) << 3;
      #pragma unroll
      for (int nj = 0; nj < 4; nj++) {
        bf16x8 kb = *(const bf16x8*)&Ks[(nj*16 + l16)*128 + swz];
        s[nj] = __builtin_amdgcn_mfma_f32_16x16x32_bf16(qa[kk], kb, s[nj], 0, 0, 0);
      }
    }

    if (it < qi) {                                // unmasked tile
      #pragma unroll
      for (int nj = 0; nj < 4; nj++) {
        #pragma unroll
        for (int r = 0; r < 4; r++) {
          float p = EXP2F(s[nj][r]);
          l[r] += p;
          const int row = quad*4 + r, col = nj*16 + l16;
          Pw[row*64 + (((col >> 3) ^ (row & 7)) << 3) + (col & 7)] = f2bf(p);
        }
      }
    } else {                                      // diagonal tile: mask
      const int s0 = it * 64;
      #pragma unroll
      for (int nj = 0; nj < 4; nj++) {
        const int key = s0 + nj*16 + l16;
        #pragma unroll
        for (int r = 0; r < 4; r++) {
          float p = (key > rowQ + quad*4 + r) ? 0.f : EXP2F(s[nj][r]);
          l[r] += p;
          const int row = quad*4 + r, col = nj*16 + l16;
          Pw[row*64 + (((col >> 3) ^ (row & 7)) << 3) + (col & 7)] = f2bf(p);
        }
      }
    }

    #pragma unroll
    for (int kk2 = 0; kk2 < 2; kk2++) {
      const int swz = ((kk2*4 + quad) ^ (l16 & 7)) << 3;
      bf16x8 pa = *(bf16x8*)&Pw[l16*64 + swz];
      #pragma unroll
      for (int e = 0; e < 8; e++) {
        bf16x8 vb = *(const bf16x8*)&Vs[(e*16 + l16)*64 + swz];
        o[e] = __builtin_amdgcn_mfma_f32_16x16x32_bf16(pa, vb, o[e], 0, 0, 0);
      }
    }
  }

  // epilogue: l-reduce, build 64x128 LDS image in Ks, b128 copy-out
  #pragma unroll
  for (int r = 0; r < 4; r++) {
    float t = l[r];
    t += __shfl_xor(t, 1); t += __shfl_xor(t, 2);
    t += __shfl_xor(t, 4); t += __shfl_xor(t, 8);
    l[r] = 1.0f / t;
  }
  __syncthreads();                                // done reading Ks/Vs
  #pragma unroll
  for (int e = 0; e < 8; e++) {
    const int c = e*2 + (l16 >> 3);
    #pragma unroll
    for (int r = 0; r < 4; r++) {
      const int lrow = w*16 + quad*4 + r;         // 0..63
      const int sub = lrow >> 5, r32 = lrow & 31;
      Ks[sub*4096 + r32*128 + ((c ^ (r32 & 15)) << 3) + (l16 & 7)] =
          f2bf(o[e][r] * l[r]);
    }
  }
  __syncthreads();
  const int st0 = b*64 + qi*2;
  #pragma unroll 2
  for (int i = tid; i < 1024; i += 256) {
    const int sub = i >> 9, rem = i & 511;
    short* dst = attnw + ((size_t)(st0 + sub)*8 + h)*4096 + rem*8;
    *(bf16x8*)dst = *(const bf16x8*)&Ks[i*8];
  }
}

// ---------------------------------------------------------------------------
// Kernel 3 (fallback only): Wu -> WuT tile images into dead Kw, after attn.
// ---------------------------------------------------------------------------
__global__ __launch_bounds__(256) void wu_prep(
    const float* __restrict__ Wu, short* __restrict__ WuT)
{
  __shared__ __align__(16) short Tt[128*128];
  wu_transpose_body(Wu, WuT, Tt, blockIdx.x, threadIdx.x);
}

// ---------------------------------------------------------------------------
// Kernel 4: out = attn @ Wu + bu -> fp32. DMA-staged, double-buffered over
// 8 k-chunks, fused bias. grid 512 (m-tile 16), 2 blocks/CU.
// ---------------------------------------------------------------------------
__global__ __launch_bounds__(256, 2) void out_proj(
    const short* __restrict__ attnw, const short* __restrict__ WuT,
    const float* __restrict__ bu, float* __restrict__ out)
{
  __shared__ __align__(16) short As2[2][2048];
  __shared__ __align__(16) short Bs2[2][16384];
  const int tid = threadIdx.x;
  const int w = tid >> 6, lane = tid & 63, quad = lane >> 4, l16 = lane & 15;
  const int m0 = (int)blockIdx.x * 16;
  const int mtile32 = m0 >> 5, half = (m0 >> 4) & 1;

  f32x4 o2[2];
  o2[0] = (f32x4){0,0,0,0}; o2[1] = (f32x4){0,0,0,0};

  {
    const short* ab = attnw + (size_t)(mtile32*8)*4096 + half*2048;
    gld16(ab + w*512 + lane*8, &As2[0][w*512]);
    #pragma unroll
    for (int cc = 0; cc < 8; cc++)
      gld16(WuT + w*4096 + cc*512 + lane*8, &Bs2[0][w*4096 + cc*512]);
  }
  int buf = 0;

  for (int kc = 0; kc < 8; kc++) {
    __syncthreads();
    if (kc < 7) {
      const short* ab = attnw + (size_t)(mtile32*8 + kc + 1)*4096 + half*2048;
      const short* bb = WuT + (size_t)(kc + 1)*16384;
      gld16(ab + w*512 + lane*8, &As2[buf^1][w*512]);
      #pragma unroll
      for (int cc = 0; cc < 8; cc++)
        gld16(bb + w*4096 + cc*512 + lane*8, &Bs2[buf^1][w*4096 + cc*512]);
    }
    const short* as = &As2[buf][0];
    const short* bs = &Bs2[buf][0];
    #pragma unroll
    for (int kk = 0; kk < 4; kk++) {
      const int swz = ((kk*4 + quad) ^ l16) << 3;
      bf16x8 a = *(const bf16x8*)&as[l16*128 + swz];
      #pragma unroll
      for (int e = 0; e < 2; e++) {
        bf16x8 bfr = *(const bf16x8*)&bs[((w*2 + e)*16 + l16)*128 + swz];
        o2[e] = __builtin_amdgcn_mfma_f32_16x16x32_bf16(a, bfr, o2[e], 0, 0, 0);
      }
    }
    buf ^= 1;
  }

  #pragma unroll
  for (int e = 0; e < 2; e++) {
    const int n = (w*2 + e)*16 + l16;
    const float bias = bu[n];
    #pragma unroll
    for (int r = 0; r < 4; r++) {
      const int mm = m0 + quad*4 + r;
      out[(size_t)mm*D_ + n] = o2[e][r] + bias;
    }
  }
}

extern "C" void kernel_launch(void* const* d_in, const int* in_sizes, int n_in,
                              void* d_out, int out_size, void* d_ws, size_t ws_size,
                              hipStream_t stream) {
  (void)in_sizes; (void)n_in; (void)out_size;
  const float* x  = (const float*)d_in[0];
  const float* Wq = (const float*)d_in[1];
  const float* Wk = (const float*)d_in[2];
  const float* Wv = (const float*)d_in[3];
  const float* Wu = (const float*)d_in[4];
  const float* bu = (const float*)d_in[5];
  float* out = (float*)d_out;

  const size_t headElems = (size_t)B_ * H_ * T_ * D_;   // 8,388,608
  short* Qw    = (short*)d_ws;
  short* Kw    = Qw + headElems;
  short* Vw    = Kw + headElems;
  short* attnw = Vw + headElems;                        // 16 MB (tiled images)
  short* xbf = attnw;                                   // prep outputs live in
  short* WT  = attnw + 1048576;                         // not-yet-written attnw

  // WuT: own region past the 64 MB map if ws allows (prep fills it, no
  // wu_prep launch); else dead-Kw reuse after attn (extra launch).
  const bool extraWu = ws_size >= (64ull << 20) + (1ull << 20);
  short* WuT = extraWu ? (short*)((char*)d_ws + (64ull << 20)) : Kw;

  prep<<<dim3(extraWu ? 96 : 88), 256, 0, stream>>>(x, Wq, Wk, Wv, Wu, xbf, WT, WuT);
  qkv_proj<<<dim3(64, 8), 256, 0, stream>>>(xbf, WT, Qw, Kw, Vw);
  attn_kernel<<<dim3(1024), 256, 0, stream>>>(Qw, Kw, Vw, attnw);
  if (!extraWu) wu_prep<<<dim3(8), 256, 0, stream>>>(Wu, WuT);
  out_proj<<<dim3(512), 256, 0, stream>>>(attnw, WuT, bu, out);
}